// Round 13
// baseline (139.382 us; speedup 1.0000x reference)
//
#include <hip/hip_runtime.h>

#define DIMN 1024
#define HEADS 16
#define DK 64
#define BATCH 2
#define SEQ 2048
#define MROWS (BATCH*SEQ)

typedef __bf16 bf16x8 __attribute__((ext_vector_type(8)));
typedef float f32x4 __attribute__((ext_vector_type(4)));

__device__ __forceinline__ unsigned short f2bf(float f) {
    unsigned int u = __float_as_uint(f);
    u += 0x7FFFu + ((u >> 16) & 1u);
    return (unsigned short)(u >> 16);
}

__device__ __forceinline__ f32x4 mfma16(bf16x8 a, bf16x8 b, f32x4 c) {
    return __builtin_amdgcn_mfma_f32_16x16x32_bf16(a, b, c, 0, 0, 0);
}

__device__ __forceinline__ void gload_lds16(const void* g, void* l) {
    __builtin_amdgcn_global_load_lds(
        (const __attribute__((address_space(1))) unsigned int*)g,
        (__attribute__((address_space(3))) unsigned int*)l, 16, 0, 0);
}

__device__ __forceinline__ unsigned cvtpk_bf16(float lo, float hi) {
    unsigned r;
    asm("v_cvt_pk_bf16_f32 %0, %1, %2" : "=v"(r) : "v"(lo), "v"(hi));
    return r;
}

// ---------------- fused fp32 -> bf16 conversion (7 arrays, 1 launch) [R5-proven] ----------------
__global__ __launch_bounds__(256) void cvt_all_kernel(
    const float* __restrict__ s0, const float* __restrict__ s1, const float* __restrict__ s2,
    const float* __restrict__ s3, const float* __restrict__ s4, const float* __restrict__ s5,
    const float* __restrict__ s6,
    unsigned short* __restrict__ d0, unsigned short* __restrict__ d1,
    unsigned short* __restrict__ d2, unsigned short* __restrict__ d3,
    unsigned short* __restrict__ d4, unsigned short* __restrict__ d5,
    unsigned short* __restrict__ d6) {
    int bb = blockIdx.x;
    const float* src; unsigned short* dst; int base;
    if (bb < 12288) {
        int w = bb >> 12; base = bb & 4095;
        src = (w == 0) ? s0 : (w == 1) ? s1 : s2;
        dst = (w == 0) ? d0 : (w == 1) ? d1 : d2;
    } else {
        int w = (bb - 12288) >> 10; base = bb & 1023;
        src = (w == 0) ? s3 : (w == 1) ? s4 : (w == 2) ? s5 : s6;
        dst = (w == 0) ? d3 : (w == 1) ? d4 : (w == 2) ? d5 : d6;
    }
    int i = (base * 256 + threadIdx.x) * 4;
    float4 v = *reinterpret_cast<const float4*>(src + i);
    ushort4 o;
    o.x = f2bf(v.x); o.y = f2bf(v.y); o.z = f2bf(v.z); o.w = f2bf(v.w);
    *reinterpret_cast<ushort4*>(dst + i) = o;
}

// ---------------- GEMM core: C = A @ W^T (+bias), bf16, BN=128, BK=32 ----------------
// LDS XOR-swizzled both-sides [R8/R9-proven]; counted-vmcnt 2-phase loop [R11/R12-proven].
template<int BMM, bool OUT_F32, bool BIAS>
__device__ __forceinline__ void gemm_core(
    const unsigned short* __restrict__ A, const unsigned short* __restrict__ W,
    void* __restrict__ Cv, const float* __restrict__ bias, float oscale,
    unsigned short (&Asm)[2][BMM * 32], unsigned short (&Bsm)[2][128 * 32]) {
    const int tid = threadIdx.x, wid = tid >> 6, lane = tid & 63;
    const int m0 = blockIdx.x * BMM, n0 = blockIdx.y * 128;
    constexpr int MR = BMM / 32;
    const int wr = (wid >> 1) * (BMM / 2), wc = (wid & 1) * 64;
    const int lrow = lane & 15, g = lane >> 4;

    f32x4 acc[MR][4];
#pragma unroll
    for (int m = 0; m < MR; m++)
#pragma unroll
        for (int n = 0; n < 4; n++) acc[m][n] = f32x4{0.f, 0.f, 0.f, 0.f};

    auto stageA = [&](int buf, int k0) {
#pragma unroll
        for (int jj = 0; jj < BMM / 64; jj++) {
            int off = jj * 4096 + wid * 1024 + lane * 16;
            int row = off >> 6;                       // 64B rows (32 bf16)
            int sch = ((off >> 4) & 3) ^ ((row >> 1) & 3);
            gload_lds16(A + (size_t)(m0 + row) * DIMN + k0 + sch * 8,
                        (char*)&Asm[buf][0] + jj * 4096 + wid * 1024);
        }
    };
    auto stageB = [&](int buf, int k0) {
#pragma unroll
        for (int jj = 0; jj < 2; jj++) {
            int off = jj * 4096 + wid * 1024 + lane * 16;
            int row = off >> 6;
            int sch = ((off >> 4) & 3) ^ ((row >> 1) & 3);
            gload_lds16(W + (size_t)(n0 + row) * DIMN + k0 + sch * 8,
                        (char*)&Bsm[buf][0] + jj * 4096 + wid * 1024);
        }
    };

    stageA(0, 0); stageB(0, 0);
    int cur = 0;
    for (int t = 0; t < 32; t++) {
        if (t + 1 < 32) {
            stageA(cur ^ 1, (t + 1) * 32); stageB(cur ^ 1, (t + 1) * 32);
            if constexpr ((BMM / 64 + 2) == 3)
                asm volatile("s_waitcnt vmcnt(3)" ::: "memory");
            else
                asm volatile("s_waitcnt vmcnt(4)" ::: "memory");
        } else {
            asm volatile("s_waitcnt vmcnt(0)" ::: "memory");
        }
        __builtin_amdgcn_s_barrier();        // cur's loads visible to all waves
        __builtin_amdgcn_sched_barrier(0);

        bf16x8 af[MR], bfr[4];
#pragma unroll
        for (int m = 0; m < MR; m++) {
            int row = wr + m * 16 + lrow;
            int ch = g ^ ((row >> 1) & 3);
            af[m] = *(const bf16x8*)&Asm[cur][row * 32 + ch * 8];
        }
#pragma unroll
        for (int n = 0; n < 4; n++) {
            int row = wc + n * 16 + lrow;
            int ch = g ^ ((row >> 1) & 3);
            bfr[n] = *(const bf16x8*)&Bsm[cur][row * 32 + ch * 8];
        }
#pragma unroll
        for (int m = 0; m < MR; m++)
#pragma unroll
            for (int n = 0; n < 4; n++)
                acc[m][n] = mfma16(af[m], bfr[n], acc[m][n]);

        __builtin_amdgcn_sched_barrier(0);
        __builtin_amdgcn_s_barrier();        // readers done before next overwrite
        cur ^= 1;
    }

    const int rbase = g * 4;
#pragma unroll
    for (int m = 0; m < MR; m++) {
#pragma unroll
        for (int n = 0; n < 4; n++) {
#pragma unroll
            for (int r = 0; r < 4; r++) {
                int row = m0 + wr + m * 16 + rbase + r;
                int col = n0 + wc + n * 16 + lrow;
                float v = acc[m][n][r] * oscale;
                if (BIAS) v += bias[col];
                if (OUT_F32)
                    ((float*)Cv)[(size_t)row * DIMN + col] = v;
                else
                    ((unsigned short*)Cv)[(size_t)row * DIMN + col] = f2bf(v);
            }
        }
    }
}

// fused 3-projection GEMM (bf16 A); Q output pre-scaled by 0.125*log2(e)
__global__ __launch_bounds__(256, 3) void gemm_proj3_kernel(
    const unsigned short* __restrict__ A0, const unsigned short* __restrict__ A1,
    const unsigned short* __restrict__ A2,
    const unsigned short* __restrict__ W0, const unsigned short* __restrict__ W1,
    const unsigned short* __restrict__ W2,
    unsigned short* __restrict__ C0, unsigned short* __restrict__ C1,
    unsigned short* __restrict__ C2) {
    __shared__ unsigned short Asm[2][128 * 32];
    __shared__ unsigned short Bsm[2][128 * 32];
    const int z = blockIdx.z;
    const unsigned short* A = (z == 0) ? A0 : (z == 1) ? A1 : A2;
    const unsigned short* W = (z == 0) ? W0 : (z == 1) ? W1 : W2;
    unsigned short* C = (z == 0) ? C0 : (z == 1) ? C1 : C2;
    const float os = (z == 0) ? 0.18033688011112042f : 1.0f;
    gemm_core<128, false, false>(A, W, C, (const float*)nullptr, os, Asm, Bsm);
}

__global__ __launch_bounds__(256, 2) void gemm_out_kernel(
    const unsigned short* __restrict__ A, const unsigned short* __restrict__ W,
    float* __restrict__ C, const float* __restrict__ bias) {
    __shared__ unsigned short AsmH[2][64 * 32];
    __shared__ unsigned short Bsm[2][128 * 32];
    gemm_core<64, true, true>(A, W, C, bias, 1.0f, AsmH, Bsm);
}

// ---------------- V transpose: vp[s][1024] -> vt[bh][d][s'] ----------------
__global__ __launch_bounds__(256) void vtrans_kernel(
    const unsigned short* __restrict__ vp, unsigned short* __restrict__ vt) {
    const int r0 = blockIdx.x * 64;
    const int h = blockIdx.y;
    const int b = r0 >> 11;
    const int s0 = r0 & 2047;
    __shared__ unsigned short T[64][72];
    const int tid = threadIdx.x;
#pragma unroll
    for (int jj = 0; jj < 2; jj++) {
        int idx = tid + 256 * jj;
        int row = idx >> 3, ch = idx & 7;
        uint4 v = *(const uint4*)(vp + (size_t)(r0 + row) * DIMN + h * DK + ch * 8);
        *(uint4*)&T[row][ch * 8] = v;
    }
    __syncthreads();
#pragma unroll
    for (int jj = 0; jj < 4; jj++) {
        int cid = tid + 256 * jj;
        int d = cid >> 4, rem = cid & 15;
        int G = rem >> 3, g = (rem >> 1) & 3, t = rem & 1;
        int sl = G * 32 + 16 * t + 4 * g;
        ushort4 o;
        o.x = T[sl + 0][d]; o.y = T[sl + 1][d]; o.z = T[sl + 2][d]; o.w = T[sl + 3][d];
        size_t orow = (size_t)((b * HEADS + h) * 64 + d);
        *(ushort4*)(vt + orow * SEQ + s0 + G * 32 + g * 8 + t * 4) = o;
    }
}

// ---------------- attention tile compute (proven verbatim) ----------------
template<bool DIAG>
__device__ __forceinline__ void attn_tile(
    const unsigned short* __restrict__ Kc, const unsigned short* __restrict__ Vc,
    bf16x8 qf0, bf16x8 qf1, f32x4 (&o)[4], float& lrun,
    const int c, const int g, const int k0, const int qq) {
    float p[16];
    float rs = 0.f;
#pragma unroll
    for (int t = 0; t < 4; t++) {
        const int row = t * 16 + c;
        bf16x8 ka0 = *(const bf16x8*)&Kc[row * 64 + ((g ^ (c & 7)) * 8)];
        bf16x8 ka1 = *(const bf16x8*)&Kc[row * 64 + (((4 + g) ^ (c & 7)) * 8)];
        f32x4 s = mfma16(ka0, qf0, f32x4{0.f, 0.f, 0.f, 0.f});
        s = mfma16(ka1, qf1, s);
        const int kbase = k0 + t * 16 + 4 * g;
#pragma unroll
        for (int r = 0; r < 4; r++) {
            float pe = __builtin_exp2f(s[r]);
            if (DIAG && (kbase + r) > qq) pe = 0.f;
            p[t * 4 + r] = pe;
            rs += pe;
        }
    }
    rs += __shfl_xor(rs, 16);
    rs += __shfl_xor(rs, 32);
    lrun += rs;

    unsigned pk[8];
#pragma unroll
    for (int t = 0; t < 4; t++) {
        pk[t * 2 + 0] = cvtpk_bf16(p[t * 4 + 0], p[t * 4 + 1]);
        pk[t * 2 + 1] = cvtpk_bf16(p[t * 4 + 2], p[t * 4 + 3]);
    }
#pragma unroll
    for (int ks = 0; ks < 2; ks++) {
        union { unsigned u[4]; bf16x8 v; } pa;
        pa.u[0] = pk[4 * ks + 0]; pa.u[1] = pk[4 * ks + 1];
        pa.u[2] = pk[4 * ks + 2]; pa.u[3] = pk[4 * ks + 3];
#pragma unroll
        for (int dt = 0; dt < 4; dt++) {
            const int row = dt * 16 + c;
            bf16x8 vb = *(const bf16x8*)&Vc[row * 64 + ((((ks * 4) + g) ^ (c & 7)) * 8)];
            o[dt] = mfma16(pa.v, vb, o[dt]);
        }
    }
}

// ---------------- causal flash attention: single 64-row q-tile per block ----------------
// 1024 blocks, XCD-pinned columns, interleaved balanced decode (R9-proven:
// per column q-tiles issue 0,31,1,30,... -> consecutive block pairs = 33 tiles
// -> uniform CU load). Counted-vmcnt 2-phase loop (R10-proven). 32KB LDS +
// (256,4) -> 4 resident blocks/CU = 4 independent barrier groups for TLP.
__global__ __launch_bounds__(256, 4) void attn_kernel(
    const unsigned short* __restrict__ qp, const unsigned short* __restrict__ kp,
    const unsigned short* __restrict__ vt, unsigned short* __restrict__ ao) {
    const int tid = threadIdx.x, wid = tid >> 6, lane = tid & 63;
    const int c = lane & 15, g = lane >> 4;
    const int blk = blockIdx.x;            // 0..1023
    const int x = blk & 7;                 // XCD pin
    const int t = blk >> 3;                // 0..127
    const int bh = x + 8 * (t >> 5);       // column 0..31
    const int s = t & 31;                  // 0..31
    const int hs = s >> 1;
    const int qblk = (s & 1) ? (31 - hs) : hs;   // 0,31,1,30,...
    const int q0 = qblk * 64;
    const int b = bh >> 4, h = bh & 15;

    __shared__ unsigned short Kt[2][64 * 64];
    __shared__ unsigned short Vt[2][64 * 64];

    const unsigned short* qrow = qp + (size_t)(b * SEQ + q0 + wid * 16 + c) * DIMN + h * DK;
    bf16x8 qf0 = *(const bf16x8*)(qrow + g * 8);
    bf16x8 qf1 = *(const bf16x8*)(qrow + 32 + g * 8);

    f32x4 o[4];
#pragma unroll
    for (int dt = 0; dt < 4; dt++) o[dt] = f32x4{0.f, 0.f, 0.f, 0.f};
    float lrun = 0.f;

    const int nkt = qblk + 1;
    const int qq = q0 + wid * 16 + c;

    auto stage = [&](int buf, int k0) {
#pragma unroll
        for (int jj = 0; jj < 2; jj++) {
            int boff = (jj * 4 + wid) * 1024;
            int off = boff + lane * 16;
            int row = off >> 7;
            int sch = ((off >> 4) & 7) ^ (row & 7);
            gload_lds16(kp + (size_t)(b * SEQ + k0 + row) * DIMN + h * DK + sch * 8,
                        (char*)&Kt[buf][0] + boff);
            gload_lds16(vt + (size_t)(bh * 64 + row) * SEQ + k0 + sch * 8,
                        (char*)&Vt[buf][0] + boff);
        }
    };

    stage(0, 0);   // 4 loads/wave in flight
    int cur = 0;
    for (int kt = 0; kt < nkt; kt++) {
        if (kt + 1 < nkt) {
            stage(cur ^ 1, (kt + 1) * 64);   // +4 -> 8 outstanding
            asm volatile("s_waitcnt vmcnt(4)" ::: "memory");  // cur's 4 landed
        } else {
            asm volatile("s_waitcnt vmcnt(0)" ::: "memory");
        }
        __builtin_amdgcn_s_barrier();        // all waves' cur loads visible
        __builtin_amdgcn_sched_barrier(0);

        const int k0 = kt * 64;
        const unsigned short* Kc = &Kt[cur][0];
        const unsigned short* Vc = &Vt[cur][0];

        if (kt == nkt - 1)
            attn_tile<true>(Kc, Vc, qf0, qf1, o, lrun, c, g, k0, qq);
        else
            attn_tile<false>(Kc, Vc, qf0, qf1, o, lrun, c, g, k0, qq);

        __builtin_amdgcn_sched_barrier(0);
        __builtin_amdgcn_s_barrier();        // readers done before next overwrite
        cur ^= 1;
    }

    float lr[4];
#pragma unroll
    for (int r = 0; r < 4; r++) lr[r] = 1.0f / __shfl(lrun, 4 * g + r);
#pragma unroll
    for (int dt = 0; dt < 4; dt++)
#pragma unroll
        for (int r = 0; r < 4; r++)
            ao[(size_t)(b * SEQ + q0 + wid * 16 + 4 * g + r) * DIMN + h * DK + dt * 16 + c] =
                f2bf(o[dt][r] * lr[r]);
}

// ---------------- launch ----------------
extern "C" void kernel_launch(void* const* d_in, const int* in_sizes, int n_in,
                              void* d_out, int out_size, void* d_ws, size_t ws_size,
                              hipStream_t stream) {
    const float* Q  = (const float*)d_in[0];
    const float* K  = (const float*)d_in[1];
    const float* V  = (const float*)d_in[2];
    const float* wq = (const float*)d_in[4];
    const float* wk = (const float*)d_in[5];
    const float* wv = (const float*)d_in[6];
    const float* wo = (const float*)d_in[7];
    const float* wob = (const float*)d_in[8];

    char* ws = (char*)d_ws;
    const size_t SZ_ACT = (size_t)MROWS * DIMN * 2;  // 8MB
    const size_t SZ_W   = (size_t)DIMN * DIMN * 2;   // 2MB
    unsigned short* Qb  = (unsigned short*)(ws);
    unsigned short* Kb  = (unsigned short*)(ws + SZ_ACT);
    unsigned short* Vb  = (unsigned short*)(ws + 2 * SZ_ACT);
    unsigned short* Wqb = (unsigned short*)(ws + 3 * SZ_ACT);
    unsigned short* Wkb = (unsigned short*)(ws + 3 * SZ_ACT + SZ_W);
    unsigned short* Wvb = (unsigned short*)(ws + 3 * SZ_ACT + 2 * SZ_W);
    unsigned short* Wob = (unsigned short*)(ws + 3 * SZ_ACT + 3 * SZ_W);
    unsigned short* qp  = (unsigned short*)(ws + 3 * SZ_ACT + 4 * SZ_W);
    unsigned short* kp  = (unsigned short*)(ws + 4 * SZ_ACT + 4 * SZ_W);
    unsigned short* vp  = (unsigned short*)(ws + 5 * SZ_ACT + 4 * SZ_W);
    unsigned short* vt  = Vb;   // alias: Vb dead after V projection
    unsigned short* aob = Qb;   // alias: Qb dead after Q projection

    cvt_all_kernel<<<16384, 256, 0, stream>>>(Q, K, V, wq, wk, wv, wo,
                                              Qb, Kb, Vb, Wqb, Wkb, Wvb, Wob);

    dim3 gp(MROWS / 128, DIMN / 128, 3);
    gemm_proj3_kernel<<<gp, 256, 0, stream>>>(Qb, Kb, Vb, Wqb, Wkb, Wvb, qp, kp, vp);

    dim3 gt(MROWS / 64, HEADS);
    vtrans_kernel<<<gt, 256, 0, stream>>>(vp, vt);

    attn_kernel<<<1024, 256, 0, stream>>>(qp, kp, vt, aob);

    dim3 go(MROWS / 64, DIMN / 128);
    gemm_out_kernel<<<go, 256, 0, stream>>>(aob, Wob, (float*)d_out, wob);
}

// Round 14
// 127.780 us; speedup vs baseline: 1.0908x; 1.0908x over previous
//
#include <hip/hip_runtime.h>

#define DIMN 1024
#define HEADS 16
#define DK 64
#define BATCH 2
#define SEQ 2048
#define MROWS (BATCH*SEQ)

typedef __bf16 bf16x8 __attribute__((ext_vector_type(8)));
typedef float f32x4 __attribute__((ext_vector_type(4)));

__device__ __forceinline__ unsigned short f2bf(float f) {
    unsigned int u = __float_as_uint(f);
    u += 0x7FFFu + ((u >> 16) & 1u);
    return (unsigned short)(u >> 16);
}

__device__ __forceinline__ f32x4 mfma16(bf16x8 a, bf16x8 b, f32x4 c) {
    return __builtin_amdgcn_mfma_f32_16x16x32_bf16(a, b, c, 0, 0, 0);
}

__device__ __forceinline__ void gload_lds16(const void* g, void* l) {
    __builtin_amdgcn_global_load_lds(
        (const __attribute__((address_space(1))) unsigned int*)g,
        (__attribute__((address_space(3))) unsigned int*)l, 16, 0, 0);
}

__device__ __forceinline__ unsigned cvtpk_bf16(float lo, float hi) {
    unsigned r;
    asm("v_cvt_pk_bf16_f32 %0, %1, %2" : "=v"(r) : "v"(lo), "v"(hi));
    return r;
}

// ---------------- fused fp32 -> bf16 conversion (7 arrays, 1 launch) [R5/R12-proven] ----------------
__global__ __launch_bounds__(256) void cvt_all_kernel(
    const float* __restrict__ s0, const float* __restrict__ s1, const float* __restrict__ s2,
    const float* __restrict__ s3, const float* __restrict__ s4, const float* __restrict__ s5,
    const float* __restrict__ s6,
    unsigned short* __restrict__ d0, unsigned short* __restrict__ d1,
    unsigned short* __restrict__ d2, unsigned short* __restrict__ d3,
    unsigned short* __restrict__ d4, unsigned short* __restrict__ d5,
    unsigned short* __restrict__ d6) {
    int bb = blockIdx.x;
    const float* src; unsigned short* dst; int base;
    if (bb < 12288) {
        int w = bb >> 12; base = bb & 4095;
        src = (w == 0) ? s0 : (w == 1) ? s1 : s2;
        dst = (w == 0) ? d0 : (w == 1) ? d1 : d2;
    } else {
        int w = (bb - 12288) >> 10; base = bb & 1023;
        src = (w == 0) ? s3 : (w == 1) ? s4 : (w == 2) ? s5 : s6;
        dst = (w == 0) ? d3 : (w == 1) ? d4 : (w == 2) ? d5 : d6;
    }
    int i = (base * 256 + threadIdx.x) * 4;
    float4 v = *reinterpret_cast<const float4*>(src + i);
    ushort4 o;
    o.x = f2bf(v.x); o.y = f2bf(v.y); o.z = f2bf(v.z); o.w = f2bf(v.w);
    *reinterpret_cast<ushort4*>(dst + i) = o;
}

// ---------------- GEMM core: C = A @ W^T (+bias), bf16, BN=128, BK=32 ----------------
// LDS XOR-swizzled both-sides [R8/R9-proven]; counted-vmcnt 2-phase loop [R11/R12-proven].
template<int BMM, bool OUT_F32, bool BIAS>
__device__ __forceinline__ void gemm_core(
    const unsigned short* __restrict__ A, const unsigned short* __restrict__ W,
    void* __restrict__ Cv, const float* __restrict__ bias, float oscale,
    unsigned short (&Asm)[2][BMM * 32], unsigned short (&Bsm)[2][128 * 32]) {
    const int tid = threadIdx.x, wid = tid >> 6, lane = tid & 63;
    const int m0 = blockIdx.x * BMM, n0 = blockIdx.y * 128;
    constexpr int MR = BMM / 32;
    const int wr = (wid >> 1) * (BMM / 2), wc = (wid & 1) * 64;
    const int lrow = lane & 15, g = lane >> 4;

    f32x4 acc[MR][4];
#pragma unroll
    for (int m = 0; m < MR; m++)
#pragma unroll
        for (int n = 0; n < 4; n++) acc[m][n] = f32x4{0.f, 0.f, 0.f, 0.f};

    auto stageA = [&](int buf, int k0) {
#pragma unroll
        for (int jj = 0; jj < BMM / 64; jj++) {
            int off = jj * 4096 + wid * 1024 + lane * 16;
            int row = off >> 6;                       // 64B rows (32 bf16)
            int sch = ((off >> 4) & 3) ^ ((row >> 1) & 3);
            gload_lds16(A + (size_t)(m0 + row) * DIMN + k0 + sch * 8,
                        (char*)&Asm[buf][0] + jj * 4096 + wid * 1024);
        }
    };
    auto stageB = [&](int buf, int k0) {
#pragma unroll
        for (int jj = 0; jj < 2; jj++) {
            int off = jj * 4096 + wid * 1024 + lane * 16;
            int row = off >> 6;
            int sch = ((off >> 4) & 3) ^ ((row >> 1) & 3);
            gload_lds16(W + (size_t)(n0 + row) * DIMN + k0 + sch * 8,
                        (char*)&Bsm[buf][0] + jj * 4096 + wid * 1024);
        }
    };

    stageA(0, 0); stageB(0, 0);
    int cur = 0;
    for (int t = 0; t < 32; t++) {
        if (t + 1 < 32) {
            stageA(cur ^ 1, (t + 1) * 32); stageB(cur ^ 1, (t + 1) * 32);
            if constexpr ((BMM / 64 + 2) == 3)
                asm volatile("s_waitcnt vmcnt(3)" ::: "memory");
            else
                asm volatile("s_waitcnt vmcnt(4)" ::: "memory");
        } else {
            asm volatile("s_waitcnt vmcnt(0)" ::: "memory");
        }
        __builtin_amdgcn_s_barrier();        // cur's loads visible to all waves
        __builtin_amdgcn_sched_barrier(0);

        bf16x8 af[MR], bfr[4];
#pragma unroll
        for (int m = 0; m < MR; m++) {
            int row = wr + m * 16 + lrow;
            int ch = g ^ ((row >> 1) & 3);
            af[m] = *(const bf16x8*)&Asm[cur][row * 32 + ch * 8];
        }
#pragma unroll
        for (int n = 0; n < 4; n++) {
            int row = wc + n * 16 + lrow;
            int ch = g ^ ((row >> 1) & 3);
            bfr[n] = *(const bf16x8*)&Bsm[cur][row * 32 + ch * 8];
        }
#pragma unroll
        for (int m = 0; m < MR; m++)
#pragma unroll
            for (int n = 0; n < 4; n++)
                acc[m][n] = mfma16(af[m], bfr[n], acc[m][n]);

        __builtin_amdgcn_sched_barrier(0);
        __builtin_amdgcn_s_barrier();        // readers done before next overwrite
        cur ^= 1;
    }

    const int rbase = g * 4;
#pragma unroll
    for (int m = 0; m < MR; m++) {
#pragma unroll
        for (int n = 0; n < 4; n++) {
#pragma unroll
            for (int r = 0; r < 4; r++) {
                int row = m0 + wr + m * 16 + rbase + r;
                int col = n0 + wc + n * 16 + lrow;
                float v = acc[m][n][r] * oscale;
                if (BIAS) v += bias[col];
                if (OUT_F32)
                    ((float*)Cv)[(size_t)row * DIMN + col] = v;
                else
                    ((unsigned short*)Cv)[(size_t)row * DIMN + col] = f2bf(v);
            }
        }
    }
}

// fused 3-projection GEMM (bf16 A); Q output pre-scaled by 0.125*log2(e)
__global__ __launch_bounds__(256, 3) void gemm_proj3_kernel(
    const unsigned short* __restrict__ A0, const unsigned short* __restrict__ A1,
    const unsigned short* __restrict__ A2,
    const unsigned short* __restrict__ W0, const unsigned short* __restrict__ W1,
    const unsigned short* __restrict__ W2,
    unsigned short* __restrict__ C0, unsigned short* __restrict__ C1,
    unsigned short* __restrict__ C2) {
    __shared__ unsigned short Asm[2][128 * 32];
    __shared__ unsigned short Bsm[2][128 * 32];
    const int z = blockIdx.z;
    const unsigned short* A = (z == 0) ? A0 : (z == 1) ? A1 : A2;
    const unsigned short* W = (z == 0) ? W0 : (z == 1) ? W1 : W2;
    unsigned short* C = (z == 0) ? C0 : (z == 1) ? C1 : C2;
    const float os = (z == 0) ? 0.18033688011112042f : 1.0f;
    gemm_core<128, false, false>(A, W, C, (const float*)nullptr, os, Asm, Bsm);
}

__global__ __launch_bounds__(256, 2) void gemm_out_kernel(
    const unsigned short* __restrict__ A, const unsigned short* __restrict__ W,
    float* __restrict__ C, const float* __restrict__ bias) {
    __shared__ unsigned short AsmH[2][64 * 32];
    __shared__ unsigned short Bsm[2][128 * 32];
    gemm_core<64, true, true>(A, W, C, bias, 1.0f, AsmH, Bsm);
}

// ---------------- V transpose: vp[s][1024] -> vt[bh][d][s'] ----------------
__global__ __launch_bounds__(256) void vtrans_kernel(
    const unsigned short* __restrict__ vp, unsigned short* __restrict__ vt) {
    const int r0 = blockIdx.x * 64;
    const int h = blockIdx.y;
    const int b = r0 >> 11;
    const int s0 = r0 & 2047;
    __shared__ unsigned short T[64][72];
    const int tid = threadIdx.x;
#pragma unroll
    for (int jj = 0; jj < 2; jj++) {
        int idx = tid + 256 * jj;
        int row = idx >> 3, ch = idx & 7;
        uint4 v = *(const uint4*)(vp + (size_t)(r0 + row) * DIMN + h * DK + ch * 8);
        *(uint4*)&T[row][ch * 8] = v;
    }
    __syncthreads();
#pragma unroll
    for (int jj = 0; jj < 4; jj++) {
        int cid = tid + 256 * jj;
        int d = cid >> 4, rem = cid & 15;
        int G = rem >> 3, g = (rem >> 1) & 3, t = rem & 1;
        int sl = G * 32 + 16 * t + 4 * g;
        ushort4 o;
        o.x = T[sl + 0][d]; o.y = T[sl + 1][d]; o.z = T[sl + 2][d]; o.w = T[sl + 3][d];
        size_t orow = (size_t)((b * HEADS + h) * 64 + d);
        *(ushort4*)(vt + orow * SEQ + s0 + G * 32 + g * 8 + t * 4) = o;
    }
}

// ---------------- attention tile compute (proven verbatim) ----------------
template<bool DIAG>
__device__ __forceinline__ void attn_tile(
    const unsigned short* __restrict__ Kc, const unsigned short* __restrict__ Vc,
    bf16x8 qf0, bf16x8 qf1, f32x4 (&o)[4], float& lrun,
    const int c, const int g, const int k0, const int qq) {
    float p[16];
    float rs = 0.f;
#pragma unroll
    for (int t = 0; t < 4; t++) {
        const int row = t * 16 + c;
        bf16x8 ka0 = *(const bf16x8*)&Kc[row * 64 + ((g ^ (c & 7)) * 8)];
        bf16x8 ka1 = *(const bf16x8*)&Kc[row * 64 + (((4 + g) ^ (c & 7)) * 8)];
        f32x4 s = mfma16(ka0, qf0, f32x4{0.f, 0.f, 0.f, 0.f});
        s = mfma16(ka1, qf1, s);
        const int kbase = k0 + t * 16 + 4 * g;
#pragma unroll
        for (int r = 0; r < 4; r++) {
            float pe = __builtin_exp2f(s[r]);
            if (DIAG && (kbase + r) > qq) pe = 0.f;
            p[t * 4 + r] = pe;
            rs += pe;
        }
    }
    rs += __shfl_xor(rs, 16);
    rs += __shfl_xor(rs, 32);
    lrun += rs;

    unsigned pk[8];
#pragma unroll
    for (int t = 0; t < 4; t++) {
        pk[t * 2 + 0] = cvtpk_bf16(p[t * 4 + 0], p[t * 4 + 1]);
        pk[t * 2 + 1] = cvtpk_bf16(p[t * 4 + 2], p[t * 4 + 3]);
    }
#pragma unroll
    for (int ks = 0; ks < 2; ks++) {
        union { unsigned u[4]; bf16x8 v; } pa;
        pa.u[0] = pk[4 * ks + 0]; pa.u[1] = pk[4 * ks + 1];
        pa.u[2] = pk[4 * ks + 2]; pa.u[3] = pk[4 * ks + 3];
#pragma unroll
        for (int dt = 0; dt < 4; dt++) {
            const int row = dt * 16 + c;
            bf16x8 vb = *(const bf16x8*)&Vc[row * 64 + ((((ks * 4) + g) ^ (c & 7)) * 8)];
            o[dt] = mfma16(pa.v, vb, o[dt]);
        }
    }
}

// ---------------- causal flash attention, paired q-tiles (R10-passed, verbatim) ----------------
// depth-1 counted-vmcnt 2-phase loop; 2 LDS buffers, 512 blocks x 256 threads.
__global__ __launch_bounds__(256, 2) void attn_kernel(
    const unsigned short* __restrict__ qp, const unsigned short* __restrict__ kp,
    const unsigned short* __restrict__ vt, unsigned short* __restrict__ ao) {
    const int tid = threadIdx.x, wid = tid >> 6, lane = tid & 63;
    const int c = lane & 15, g = lane >> 4;
    const int blk = blockIdx.x;            // 0..511
    const int kk = blk >> 3;               // 0..63
    const int bh = (blk & 7) + 8 * (kk >> 4);  // column -> XCD pin
    const int j = kk & 15;                 // pair index 0..15
    const int qA = j * 64;                 // light q-tile (j+1 kv tiles)
    const int qB = (31 - j) * 64;          // heavy q-tile (32-j kv tiles)
    const int b = bh >> 4, h = bh & 15;

    __shared__ unsigned short Kt[2][64 * 64];
    __shared__ unsigned short Vt[2][64 * 64];

    const unsigned short* qrowA = qp + (size_t)(b * SEQ + qA + wid * 16 + c) * DIMN + h * DK;
    bf16x8 qfA0 = *(const bf16x8*)(qrowA + g * 8);
    bf16x8 qfA1 = *(const bf16x8*)(qrowA + 32 + g * 8);
    const unsigned short* qrowB = qp + (size_t)(b * SEQ + qB + wid * 16 + c) * DIMN + h * DK;
    bf16x8 qfB0 = *(const bf16x8*)(qrowB + g * 8);
    bf16x8 qfB1 = *(const bf16x8*)(qrowB + 32 + g * 8);

    f32x4 oA[4], oB[4];
#pragma unroll
    for (int dt = 0; dt < 4; dt++) {
        oA[dt] = f32x4{0.f, 0.f, 0.f, 0.f};
        oB[dt] = f32x4{0.f, 0.f, 0.f, 0.f};
    }
    float lrunA = 0.f, lrunB = 0.f;

    const int nktB = 32 - j;
    const int qqA = qA + wid * 16 + c;
    const int qqB = qB + wid * 16 + c;

    auto stage = [&](int buf, int k0) {
#pragma unroll
        for (int jj = 0; jj < 2; jj++) {
            int boff = (jj * 4 + wid) * 1024;
            int off = boff + lane * 16;
            int row = off >> 7;
            int sch = ((off >> 4) & 7) ^ (row & 7);
            gload_lds16(kp + (size_t)(b * SEQ + k0 + row) * DIMN + h * DK + sch * 8,
                        (char*)&Kt[buf][0] + boff);
            gload_lds16(vt + (size_t)(bh * 64 + row) * SEQ + k0 + sch * 8,
                        (char*)&Vt[buf][0] + boff);
        }
    };

    stage(0, 0);   // 4 loads/wave in flight; waited inside the loop
    int cur = 0;
    for (int kt = 0; kt < nktB; kt++) {
        const bool pf = (kt + 1 < nktB);
        if (pf) {
            stage(cur ^ 1, (kt + 1) * 64);   // +4 loads -> 8 outstanding
            asm volatile("s_waitcnt vmcnt(4)" ::: "memory");  // cur's 4 landed
        } else {
            asm volatile("s_waitcnt vmcnt(0)" ::: "memory");
        }
        __builtin_amdgcn_s_barrier();        // all waves' cur loads visible
        __builtin_amdgcn_sched_barrier(0);

        const int k0 = kt * 64;
        const unsigned short* Kc = &Kt[cur][0];
        const unsigned short* Vc = &Vt[cur][0];

        if (kt == nktB - 1)
            attn_tile<true>(Kc, Vc, qfB0, qfB1, oB, lrunB, c, g, k0, qqB);
        else
            attn_tile<false>(Kc, Vc, qfB0, qfB1, oB, lrunB, c, g, k0, qqB);

        if (kt < j)
            attn_tile<false>(Kc, Vc, qfA0, qfA1, oA, lrunA, c, g, k0, qqA);
        else if (kt == j)
            attn_tile<true>(Kc, Vc, qfA0, qfA1, oA, lrunA, c, g, k0, qqA);

        __builtin_amdgcn_sched_barrier(0);
        __builtin_amdgcn_s_barrier();        // readers done before next overwrite
        cur ^= 1;
    }

    float lrA[4], lrB[4];
#pragma unroll
    for (int r = 0; r < 4; r++) {
        lrA[r] = 1.0f / __shfl(lrunA, 4 * g + r);
        lrB[r] = 1.0f / __shfl(lrunB, 4 * g + r);
    }
#pragma unroll
    for (int dt = 0; dt < 4; dt++)
#pragma unroll
        for (int r = 0; r < 4; r++) {
            ao[(size_t)(b * SEQ + qA + wid * 16 + 4 * g + r) * DIMN + h * DK + dt * 16 + c] =
                f2bf(oA[dt][r] * lrA[r]);
            ao[(size_t)(b * SEQ + qB + wid * 16 + 4 * g + r) * DIMN + h * DK + dt * 16 + c] =
                f2bf(oB[dt][r] * lrB[r]);
        }
}

// ---------------- launch ----------------
extern "C" void kernel_launch(void* const* d_in, const int* in_sizes, int n_in,
                              void* d_out, int out_size, void* d_ws, size_t ws_size,
                              hipStream_t stream) {
    const float* Q  = (const float*)d_in[0];
    const float* K  = (const float*)d_in[1];
    const float* V  = (const float*)d_in[2];
    const float* wq = (const float*)d_in[4];
    const float* wk = (const float*)d_in[5];
    const float* wv = (const float*)d_in[6];
    const float* wo = (const float*)d_in[7];
    const float* wob = (const float*)d_in[8];

    char* ws = (char*)d_ws;
    const size_t SZ_ACT = (size_t)MROWS * DIMN * 2;  // 8MB
    const size_t SZ_W   = (size_t)DIMN * DIMN * 2;   // 2MB
    unsigned short* Qb  = (unsigned short*)(ws);
    unsigned short* Kb  = (unsigned short*)(ws + SZ_ACT);
    unsigned short* Vb  = (unsigned short*)(ws + 2 * SZ_ACT);
    unsigned short* Wqb = (unsigned short*)(ws + 3 * SZ_ACT);
    unsigned short* Wkb = (unsigned short*)(ws + 3 * SZ_ACT + SZ_W);
    unsigned short* Wvb = (unsigned short*)(ws + 3 * SZ_ACT + 2 * SZ_W);
    unsigned short* Wob = (unsigned short*)(ws + 3 * SZ_ACT + 3 * SZ_W);
    unsigned short* qp  = (unsigned short*)(ws + 3 * SZ_ACT + 4 * SZ_W);
    unsigned short* kp  = (unsigned short*)(ws + 4 * SZ_ACT + 4 * SZ_W);
    unsigned short* vp  = (unsigned short*)(ws + 5 * SZ_ACT + 4 * SZ_W);
    unsigned short* vt  = Vb;   // alias: Vb dead after V projection
    unsigned short* aob = Qb;   // alias: Qb dead after Q projection

    cvt_all_kernel<<<16384, 256, 0, stream>>>(Q, K, V, wq, wk, wv, wo,
                                              Qb, Kb, Vb, Wqb, Wkb, Wvb, Wob);

    dim3 gp(MROWS / 128, DIMN / 128, 3);
    gemm_proj3_kernel<<<gp, 256, 0, stream>>>(Qb, Kb, Vb, Wqb, Wkb, Wvb, qp, kp, vp);

    dim3 gt(MROWS / 64, HEADS);
    vtrans_kernel<<<gt, 256, 0, stream>>>(vp, vt);

    attn_kernel<<<512, 256, 0, stream>>>(qp, kp, vt, aob);

    dim3 go(MROWS / 64, DIMN / 128);
    gemm_out_kernel<<<go, 256, 0, stream>>>(aob, Wob, (float*)d_out, wob);
}

// Round 15
// 124.589 us; speedup vs baseline: 1.1187x; 1.0256x over previous
//
#include <hip/hip_runtime.h>

#define DIMN 1024
#define HEADS 16
#define DK 64
#define BATCH 2
#define SEQ 2048
#define MROWS (BATCH*SEQ)

typedef __bf16 bf16x8 __attribute__((ext_vector_type(8)));
typedef float f32x4 __attribute__((ext_vector_type(4)));

__device__ __forceinline__ unsigned short f2bf(float f) {
    unsigned int u = __float_as_uint(f);
    u += 0x7FFFu + ((u >> 16) & 1u);
    return (unsigned short)(u >> 16);
}

__device__ __forceinline__ f32x4 mfma16(bf16x8 a, bf16x8 b, f32x4 c) {
    return __builtin_amdgcn_mfma_f32_16x16x32_bf16(a, b, c, 0, 0, 0);
}

__device__ __forceinline__ void gload_lds16(const void* g, void* l) {
    __builtin_amdgcn_global_load_lds(
        (const __attribute__((address_space(1))) unsigned int*)g,
        (__attribute__((address_space(3))) unsigned int*)l, 16, 0, 0);
}

__device__ __forceinline__ unsigned cvtpk_bf16(float lo, float hi) {
    unsigned r;
    asm("v_cvt_pk_bf16_f32 %0, %1, %2" : "=v"(r) : "v"(lo), "v"(hi));
    return r;
}

// ---------------- fused fp32 -> bf16 conversion (7 arrays, 1 launch) [R5/R12-proven] ----------------
__global__ __launch_bounds__(256) void cvt_all_kernel(
    const float* __restrict__ s0, const float* __restrict__ s1, const float* __restrict__ s2,
    const float* __restrict__ s3, const float* __restrict__ s4, const float* __restrict__ s5,
    const float* __restrict__ s6,
    unsigned short* __restrict__ d0, unsigned short* __restrict__ d1,
    unsigned short* __restrict__ d2, unsigned short* __restrict__ d3,
    unsigned short* __restrict__ d4, unsigned short* __restrict__ d5,
    unsigned short* __restrict__ d6) {
    int bb = blockIdx.x;
    const float* src; unsigned short* dst; int base;
    if (bb < 12288) {
        int w = bb >> 12; base = bb & 4095;
        src = (w == 0) ? s0 : (w == 1) ? s1 : s2;
        dst = (w == 0) ? d0 : (w == 1) ? d1 : d2;
    } else {
        int w = (bb - 12288) >> 10; base = bb & 1023;
        src = (w == 0) ? s3 : (w == 1) ? s4 : (w == 2) ? s5 : s6;
        dst = (w == 0) ? d3 : (w == 1) ? d4 : (w == 2) ? d5 : d6;
    }
    int i = (base * 256 + threadIdx.x) * 4;
    float4 v = *reinterpret_cast<const float4*>(src + i);
    ushort4 o;
    o.x = f2bf(v.x); o.y = f2bf(v.y); o.z = f2bf(v.z); o.w = f2bf(v.w);
    *reinterpret_cast<ushort4*>(dst + i) = o;
}

// ---------------- GEMM core: C = A @ W^T (+bias), bf16, BN=128, BK=32 ----------------
// LDS XOR-swizzled both-sides [R8/R9-proven]; counted-vmcnt 2-phase loop [R11/R12-proven].
template<int BMM, bool OUT_F32, bool BIAS>
__device__ __forceinline__ void gemm_core(
    const unsigned short* __restrict__ A, const unsigned short* __restrict__ W,
    void* __restrict__ Cv, const float* __restrict__ bias, float oscale,
    unsigned short (&Asm)[2][BMM * 32], unsigned short (&Bsm)[2][128 * 32]) {
    const int tid = threadIdx.x, wid = tid >> 6, lane = tid & 63;
    const int m0 = blockIdx.x * BMM, n0 = blockIdx.y * 128;
    constexpr int MR = BMM / 32;
    const int wr = (wid >> 1) * (BMM / 2), wc = (wid & 1) * 64;
    const int lrow = lane & 15, g = lane >> 4;

    f32x4 acc[MR][4];
#pragma unroll
    for (int m = 0; m < MR; m++)
#pragma unroll
        for (int n = 0; n < 4; n++) acc[m][n] = f32x4{0.f, 0.f, 0.f, 0.f};

    auto stageA = [&](int buf, int k0) {
#pragma unroll
        for (int jj = 0; jj < BMM / 64; jj++) {
            int off = jj * 4096 + wid * 1024 + lane * 16;
            int row = off >> 6;                       // 64B rows (32 bf16)
            int sch = ((off >> 4) & 3) ^ ((row >> 1) & 3);
            gload_lds16(A + (size_t)(m0 + row) * DIMN + k0 + sch * 8,
                        (char*)&Asm[buf][0] + jj * 4096 + wid * 1024);
        }
    };
    auto stageB = [&](int buf, int k0) {
#pragma unroll
        for (int jj = 0; jj < 2; jj++) {
            int off = jj * 4096 + wid * 1024 + lane * 16;
            int row = off >> 6;
            int sch = ((off >> 4) & 3) ^ ((row >> 1) & 3);
            gload_lds16(W + (size_t)(n0 + row) * DIMN + k0 + sch * 8,
                        (char*)&Bsm[buf][0] + jj * 4096 + wid * 1024);
        }
    };

    stageA(0, 0); stageB(0, 0);
    int cur = 0;
    for (int t = 0; t < 32; t++) {
        if (t + 1 < 32) {
            stageA(cur ^ 1, (t + 1) * 32); stageB(cur ^ 1, (t + 1) * 32);
            if constexpr ((BMM / 64 + 2) == 3)
                asm volatile("s_waitcnt vmcnt(3)" ::: "memory");
            else
                asm volatile("s_waitcnt vmcnt(4)" ::: "memory");
        } else {
            asm volatile("s_waitcnt vmcnt(0)" ::: "memory");
        }
        __builtin_amdgcn_s_barrier();        // cur's loads visible to all waves
        __builtin_amdgcn_sched_barrier(0);

        bf16x8 af[MR], bfr[4];
#pragma unroll
        for (int m = 0; m < MR; m++) {
            int row = wr + m * 16 + lrow;
            int ch = g ^ ((row >> 1) & 3);
            af[m] = *(const bf16x8*)&Asm[cur][row * 32 + ch * 8];
        }
#pragma unroll
        for (int n = 0; n < 4; n++) {
            int row = wc + n * 16 + lrow;
            int ch = g ^ ((row >> 1) & 3);
            bfr[n] = *(const bf16x8*)&Bsm[cur][row * 32 + ch * 8];
        }
#pragma unroll
        for (int m = 0; m < MR; m++)
#pragma unroll
            for (int n = 0; n < 4; n++)
                acc[m][n] = mfma16(af[m], bfr[n], acc[m][n]);

        __builtin_amdgcn_sched_barrier(0);
        __builtin_amdgcn_s_barrier();        // readers done before next overwrite
        cur ^= 1;
    }

    const int rbase = g * 4;
#pragma unroll
    for (int m = 0; m < MR; m++) {
#pragma unroll
        for (int n = 0; n < 4; n++) {
#pragma unroll
            for (int r = 0; r < 4; r++) {
                int row = m0 + wr + m * 16 + rbase + r;
                int col = n0 + wc + n * 16 + lrow;
                float v = acc[m][n][r] * oscale;
                if (BIAS) v += bias[col];
                if (OUT_F32)
                    ((float*)Cv)[(size_t)row * DIMN + col] = v;
                else
                    ((unsigned short*)Cv)[(size_t)row * DIMN + col] = f2bf(v);
            }
        }
    }
}

// fused 3-projection GEMM (bf16 A); Q output pre-scaled by 0.125*log2(e)
__global__ __launch_bounds__(256, 3) void gemm_proj3_kernel(
    const unsigned short* __restrict__ A0, const unsigned short* __restrict__ A1,
    const unsigned short* __restrict__ A2,
    const unsigned short* __restrict__ W0, const unsigned short* __restrict__ W1,
    const unsigned short* __restrict__ W2,
    unsigned short* __restrict__ C0, unsigned short* __restrict__ C1,
    unsigned short* __restrict__ C2) {
    __shared__ unsigned short Asm[2][128 * 32];
    __shared__ unsigned short Bsm[2][128 * 32];
    const int z = blockIdx.z;
    const unsigned short* A = (z == 0) ? A0 : (z == 1) ? A1 : A2;
    const unsigned short* W = (z == 0) ? W0 : (z == 1) ? W1 : W2;
    unsigned short* C = (z == 0) ? C0 : (z == 1) ? C1 : C2;
    const float os = (z == 0) ? 0.18033688011112042f : 1.0f;
    gemm_core<128, false, false>(A, W, C, (const float*)nullptr, os, Asm, Bsm);
}

__global__ __launch_bounds__(256, 2) void gemm_out_kernel(
    const unsigned short* __restrict__ A, const unsigned short* __restrict__ W,
    float* __restrict__ C, const float* __restrict__ bias) {
    __shared__ unsigned short AsmH[2][64 * 32];
    __shared__ unsigned short Bsm[2][128 * 32];
    gemm_core<64, true, true>(A, W, C, bias, 1.0f, AsmH, Bsm);
}

// ---------------- V transpose: vp[s][1024] -> vt[bh][d][s'] ----------------
__global__ __launch_bounds__(256) void vtrans_kernel(
    const unsigned short* __restrict__ vp, unsigned short* __restrict__ vt) {
    const int r0 = blockIdx.x * 64;
    const int h = blockIdx.y;
    const int b = r0 >> 11;
    const int s0 = r0 & 2047;
    __shared__ unsigned short T[64][72];
    const int tid = threadIdx.x;
#pragma unroll
    for (int jj = 0; jj < 2; jj++) {
        int idx = tid + 256 * jj;
        int row = idx >> 3, ch = idx & 7;
        uint4 v = *(const uint4*)(vp + (size_t)(r0 + row) * DIMN + h * DK + ch * 8);
        *(uint4*)&T[row][ch * 8] = v;
    }
    __syncthreads();
#pragma unroll
    for (int jj = 0; jj < 4; jj++) {
        int cid = tid + 256 * jj;
        int d = cid >> 4, rem = cid & 15;
        int G = rem >> 3, g = (rem >> 1) & 3, t = rem & 1;
        int sl = G * 32 + 16 * t + 4 * g;
        ushort4 o;
        o.x = T[sl + 0][d]; o.y = T[sl + 1][d]; o.z = T[sl + 2][d]; o.w = T[sl + 3][d];
        size_t orow = (size_t)((b * HEADS + h) * 64 + d);
        *(ushort4*)(vt + orow * SEQ + s0 + G * 32 + g * 8 + t * 4) = o;
    }
}

// ---------------- attention tile compute (proven verbatim) ----------------
template<bool DIAG>
__device__ __forceinline__ void attn_tile(
    const unsigned short* __restrict__ Kc, const unsigned short* __restrict__ Vc,
    bf16x8 qf0, bf16x8 qf1, f32x4 (&o)[4], float& lrun,
    const int c, const int g, const int k0, const int qq) {
    float p[16];
    float rs = 0.f;
#pragma unroll
    for (int t = 0; t < 4; t++) {
        const int row = t * 16 + c;
        bf16x8 ka0 = *(const bf16x8*)&Kc[row * 64 + ((g ^ (c & 7)) * 8)];
        bf16x8 ka1 = *(const bf16x8*)&Kc[row * 64 + (((4 + g) ^ (c & 7)) * 8)];
        f32x4 s = mfma16(ka0, qf0, f32x4{0.f, 0.f, 0.f, 0.f});
        s = mfma16(ka1, qf1, s);
        const int kbase = k0 + t * 16 + 4 * g;
#pragma unroll
        for (int r = 0; r < 4; r++) {
            float pe = __builtin_exp2f(s[r]);
            if (DIAG && (kbase + r) > qq) pe = 0.f;
            p[t * 4 + r] = pe;
            rs += pe;
        }
    }
    rs += __shfl_xor(rs, 16);
    rs += __shfl_xor(rs, 32);
    lrun += rs;

    unsigned pk[8];
#pragma unroll
    for (int t = 0; t < 4; t++) {
        pk[t * 2 + 0] = cvtpk_bf16(p[t * 4 + 0], p[t * 4 + 1]);
        pk[t * 2 + 1] = cvtpk_bf16(p[t * 4 + 2], p[t * 4 + 3]);
    }
#pragma unroll
    for (int ks = 0; ks < 2; ks++) {
        union { unsigned u[4]; bf16x8 v; } pa;
        pa.u[0] = pk[4 * ks + 0]; pa.u[1] = pk[4 * ks + 1];
        pa.u[2] = pk[4 * ks + 2]; pa.u[3] = pk[4 * ks + 3];
#pragma unroll
        for (int dt = 0; dt < 4; dt++) {
            const int row = dt * 16 + c;
            bf16x8 vb = *(const bf16x8*)&Vc[row * 64 + ((((ks * 4) + g) ^ (c & 7)) * 8)];
            o[dt] = mfma16(pa.v, vb, o[dt]);
        }
    }
}

// ---------------- causal flash attention, paired q-tiles, 2-tiles-per-barrier ----------------
// 4-buffer ring (64KB LDS): each barrier interval computes TWO kv tiles
// back-to-back while the next two stage. Halves iteration/barrier count for
// the heavy (j=0) blocks (32 -> 16 iterations). Tile math, swizzle, decode
// all R10/R14-proven verbatim. vmcnt: 4 loads/wave per tile.
__global__ __launch_bounds__(256, 2) void attn_kernel(
    const unsigned short* __restrict__ qp, const unsigned short* __restrict__ kp,
    const unsigned short* __restrict__ vt, unsigned short* __restrict__ ao) {
    const int tid = threadIdx.x, wid = tid >> 6, lane = tid & 63;
    const int c = lane & 15, g = lane >> 4;
    const int blk = blockIdx.x;            // 0..511
    const int kk = blk >> 3;               // 0..63
    const int bh = (blk & 7) + 8 * (kk >> 4);  // column -> XCD pin
    const int j = kk & 15;                 // pair index 0..15
    const int qA = j * 64;                 // light q-tile (j+1 kv tiles)
    const int qB = (31 - j) * 64;          // heavy q-tile (32-j kv tiles)
    const int b = bh >> 4, h = bh & 15;

    __shared__ unsigned short Kt[4][64 * 64];
    __shared__ unsigned short Vt[4][64 * 64];

    const unsigned short* qrowA = qp + (size_t)(b * SEQ + qA + wid * 16 + c) * DIMN + h * DK;
    bf16x8 qfA0 = *(const bf16x8*)(qrowA + g * 8);
    bf16x8 qfA1 = *(const bf16x8*)(qrowA + 32 + g * 8);
    const unsigned short* qrowB = qp + (size_t)(b * SEQ + qB + wid * 16 + c) * DIMN + h * DK;
    bf16x8 qfB0 = *(const bf16x8*)(qrowB + g * 8);
    bf16x8 qfB1 = *(const bf16x8*)(qrowB + 32 + g * 8);

    f32x4 oA[4], oB[4];
#pragma unroll
    for (int dt = 0; dt < 4; dt++) {
        oA[dt] = f32x4{0.f, 0.f, 0.f, 0.f};
        oB[dt] = f32x4{0.f, 0.f, 0.f, 0.f};
    }
    float lrunA = 0.f, lrunB = 0.f;

    const int nkt = 32 - j;                // kv tiles for B (>= 17); A uses 0..j
    const int qqA = qA + wid * 16 + c;
    const int qqB = qB + wid * 16 + c;

    auto stage = [&](int buf, int k0) {    // 4 loads/wave [proven verbatim]
#pragma unroll
        for (int jj = 0; jj < 2; jj++) {
            int boff = (jj * 4 + wid) * 1024;
            int off = boff + lane * 16;
            int row = off >> 7;
            int sch = ((off >> 4) & 7) ^ (row & 7);
            gload_lds16(kp + (size_t)(b * SEQ + k0 + row) * DIMN + h * DK + sch * 8,
                        (char*)&Kt[buf][0] + boff);
            gload_lds16(vt + (size_t)(bh * 64 + row) * SEQ + k0 + sch * 8,
                        (char*)&Vt[buf][0] + boff);
        }
    };

    // prologue: stage tiles 0..3 (nkt >= 17, all exist)
    stage(0, 0);
    stage(1, 64);
    stage(2, 128);
    stage(3, 192);

    for (int kt = 0; kt < nkt; kt += 2) {
        // wait until tiles kt, kt+1 landed; tiles kt+2, kt+3 may stay in flight
        const int after = (kt + 4 <= nkt) ? 2 : (kt + 3 <= nkt) ? 1 : 0;  // tiles staged beyond kt+1
        if (after == 2)      asm volatile("s_waitcnt vmcnt(8)" ::: "memory");
        else if (after == 1) asm volatile("s_waitcnt vmcnt(4)" ::: "memory");
        else                 asm volatile("s_waitcnt vmcnt(0)" ::: "memory");
        __builtin_amdgcn_s_barrier();        // all waves' tiles kt,kt+1 visible
        __builtin_amdgcn_sched_barrier(0);

        for (int u = 0; u < 2; u++) {
            const int t = kt + u;
            if (t >= nkt) break;             // wave-uniform
            const int k0 = t * 64;
            const unsigned short* Kc = &Kt[t & 3][0];
            const unsigned short* Vc = &Vt[t & 3][0];

            if (t == nkt - 1)
                attn_tile<true>(Kc, Vc, qfB0, qfB1, oB, lrunB, c, g, k0, qqB);
            else
                attn_tile<false>(Kc, Vc, qfB0, qfB1, oB, lrunB, c, g, k0, qqB);

            if (t < j)
                attn_tile<false>(Kc, Vc, qfA0, qfA1, oA, lrunA, c, g, k0, qqA);
            else if (t == j)
                attn_tile<true>(Kc, Vc, qfA0, qfA1, oA, lrunA, c, g, k0, qqA);
        }

        __builtin_amdgcn_sched_barrier(0);
        __builtin_amdgcn_s_barrier();        // readers done before buffer reuse
        if (kt + 4 < nkt) stage((kt + 4) & 3, (kt + 4) * 64);
        if (kt + 5 < nkt) stage((kt + 5) & 3, (kt + 5) * 64);
    }

    float lrA[4], lrB[4];
#pragma unroll
    for (int r = 0; r < 4; r++) {
        lrA[r] = 1.0f / __shfl(lrunA, 4 * g + r);
        lrB[r] = 1.0f / __shfl(lrunB, 4 * g + r);
    }
#pragma unroll
    for (int dt = 0; dt < 4; dt++)
#pragma unroll
        for (int r = 0; r < 4; r++) {
            ao[(size_t)(b * SEQ + qA + wid * 16 + 4 * g + r) * DIMN + h * DK + dt * 16 + c] =
                f2bf(oA[dt][r] * lrA[r]);
            ao[(size_t)(b * SEQ + qB + wid * 16 + 4 * g + r) * DIMN + h * DK + dt * 16 + c] =
                f2bf(oB[dt][r] * lrB[r]);
        }
}

// ---------------- launch ----------------
extern "C" void kernel_launch(void* const* d_in, const int* in_sizes, int n_in,
                              void* d_out, int out_size, void* d_ws, size_t ws_size,
                              hipStream_t stream) {
    const float* Q  = (const float*)d_in[0];
    const float* K  = (const float*)d_in[1];
    const float* V  = (const float*)d_in[2];
    const float* wq = (const float*)d_in[4];
    const float* wk = (const float*)d_in[5];
    const float* wv = (const float*)d_in[6];
    const float* wo = (const float*)d_in[7];
    const float* wob = (const float*)d_in[8];

    char* ws = (char*)d_ws;
    const size_t SZ_ACT = (size_t)MROWS * DIMN * 2;  // 8MB
    const size_t SZ_W   = (size_t)DIMN * DIMN * 2;   // 2MB
    unsigned short* Qb  = (unsigned short*)(ws);
    unsigned short* Kb  = (unsigned short*)(ws + SZ_ACT);
    unsigned short* Vb  = (unsigned short*)(ws + 2 * SZ_ACT);
    unsigned short* Wqb = (unsigned short*)(ws + 3 * SZ_ACT);
    unsigned short* Wkb = (unsigned short*)(ws + 3 * SZ_ACT + SZ_W);
    unsigned short* Wvb = (unsigned short*)(ws + 3 * SZ_ACT + 2 * SZ_W);
    unsigned short* Wob = (unsigned short*)(ws + 3 * SZ_ACT + 3 * SZ_W);
    unsigned short* qp  = (unsigned short*)(ws + 3 * SZ_ACT + 4 * SZ_W);
    unsigned short* kp  = (unsigned short*)(ws + 4 * SZ_ACT + 4 * SZ_W);
    unsigned short* vp  = (unsigned short*)(ws + 5 * SZ_ACT + 4 * SZ_W);
    unsigned short* vt  = Vb;   // alias: Vb dead after V projection
    unsigned short* aob = Qb;   // alias: Qb dead after Q projection

    cvt_all_kernel<<<16384, 256, 0, stream>>>(Q, K, V, wq, wk, wv, wo,
                                              Qb, Kb, Vb, Wqb, Wkb, Wvb, Wob);

    dim3 gp(MROWS / 128, DIMN / 128, 3);
    gemm_proj3_kernel<<<gp, 256, 0, stream>>>(Qb, Kb, Vb, Wqb, Wkb, Wvb, qp, kp, vp);

    dim3 gt(MROWS / 64, HEADS);
    vtrans_kernel<<<gt, 256, 0, stream>>>(vp, vt);

    attn_kernel<<<512, 256, 0, stream>>>(qp, kp, vt, aob);

    dim3 go(MROWS / 64, DIMN / 128);
    gemm_out_kernel<<<go, 256, 0, stream>>>(aob, Wob, (float*)d_out, wob);
}

// Round 16
// 119.747 us; speedup vs baseline: 1.1640x; 1.0404x over previous
//
#include <hip/hip_runtime.h>

#define DIMN 1024
#define HEADS 16
#define DK 64
#define BATCH 2
#define SEQ 2048
#define MROWS (BATCH*SEQ)

typedef __bf16 bf16x8 __attribute__((ext_vector_type(8)));
typedef float f32x4 __attribute__((ext_vector_type(4)));

__device__ __forceinline__ unsigned short f2bf(float f) {
    unsigned int u = __float_as_uint(f);
    u += 0x7FFFu + ((u >> 16) & 1u);
    return (unsigned short)(u >> 16);
}

__device__ __forceinline__ f32x4 mfma16(bf16x8 a, bf16x8 b, f32x4 c) {
    return __builtin_amdgcn_mfma_f32_16x16x32_bf16(a, b, c, 0, 0, 0);
}

__device__ __forceinline__ void gload_lds16(const void* g, void* l) {
    __builtin_amdgcn_global_load_lds(
        (const __attribute__((address_space(1))) unsigned int*)g,
        (__attribute__((address_space(3))) unsigned int*)l, 16, 0, 0);
}

__device__ __forceinline__ unsigned cvtpk_bf16(float lo, float hi) {
    unsigned r;
    asm("v_cvt_pk_bf16_f32 %0, %1, %2" : "=v"(r) : "v"(lo), "v"(hi));
    return r;
}

// ---------------- fused fp32 -> bf16 conversion (7 arrays, 1 launch) [R5/R12-proven] ----------------
__global__ __launch_bounds__(256) void cvt_all_kernel(
    const float* __restrict__ s0, const float* __restrict__ s1, const float* __restrict__ s2,
    const float* __restrict__ s3, const float* __restrict__ s4, const float* __restrict__ s5,
    const float* __restrict__ s6,
    unsigned short* __restrict__ d0, unsigned short* __restrict__ d1,
    unsigned short* __restrict__ d2, unsigned short* __restrict__ d3,
    unsigned short* __restrict__ d4, unsigned short* __restrict__ d5,
    unsigned short* __restrict__ d6) {
    int bb = blockIdx.x;
    const float* src; unsigned short* dst; int base;
    if (bb < 12288) {
        int w = bb >> 12; base = bb & 4095;
        src = (w == 0) ? s0 : (w == 1) ? s1 : s2;
        dst = (w == 0) ? d0 : (w == 1) ? d1 : d2;
    } else {
        int w = (bb - 12288) >> 10; base = bb & 1023;
        src = (w == 0) ? s3 : (w == 1) ? s4 : (w == 2) ? s5 : s6;
        dst = (w == 0) ? d3 : (w == 1) ? d4 : (w == 2) ? d5 : d6;
    }
    int i = (base * 256 + threadIdx.x) * 4;
    float4 v = *reinterpret_cast<const float4*>(src + i);
    ushort4 o;
    o.x = f2bf(v.x); o.y = f2bf(v.y); o.z = f2bf(v.z); o.w = f2bf(v.w);
    *reinterpret_cast<ushort4*>(dst + i) = o;
}

// ---------------- GEMM core: C = A @ W^T (+bias), bf16, BN=128, BK=32 ----------------
// LDS XOR-swizzled both-sides [R8/R9-proven]; counted-vmcnt 2-phase loop [R11/R12-proven].
// vtmode (runtime, epilogue-only): write C in the attention V^T layout
// vt[(b*16+h)*64+d][(s & ~31) + perm(s&31)] -- byte-exact with vtrans_kernel.
template<int BMM, bool OUT_F32, bool BIAS>
__device__ __forceinline__ void gemm_core(
    const unsigned short* __restrict__ A, const unsigned short* __restrict__ W,
    void* __restrict__ Cv, const float* __restrict__ bias, float oscale, int vtmode,
    unsigned short (&Asm)[2][BMM * 32], unsigned short (&Bsm)[2][128 * 32]) {
    const int tid = threadIdx.x, wid = tid >> 6, lane = tid & 63;
    const int m0 = blockIdx.x * BMM, n0 = blockIdx.y * 128;
    constexpr int MR = BMM / 32;
    const int wr = (wid >> 1) * (BMM / 2), wc = (wid & 1) * 64;
    const int lrow = lane & 15, g = lane >> 4;

    f32x4 acc[MR][4];
#pragma unroll
    for (int m = 0; m < MR; m++)
#pragma unroll
        for (int n = 0; n < 4; n++) acc[m][n] = f32x4{0.f, 0.f, 0.f, 0.f};

    auto stageA = [&](int buf, int k0) {
#pragma unroll
        for (int jj = 0; jj < BMM / 64; jj++) {
            int off = jj * 4096 + wid * 1024 + lane * 16;
            int row = off >> 6;                       // 64B rows (32 bf16)
            int sch = ((off >> 4) & 3) ^ ((row >> 1) & 3);
            gload_lds16(A + (size_t)(m0 + row) * DIMN + k0 + sch * 8,
                        (char*)&Asm[buf][0] + jj * 4096 + wid * 1024);
        }
    };
    auto stageB = [&](int buf, int k0) {
#pragma unroll
        for (int jj = 0; jj < 2; jj++) {
            int off = jj * 4096 + wid * 1024 + lane * 16;
            int row = off >> 6;
            int sch = ((off >> 4) & 3) ^ ((row >> 1) & 3);
            gload_lds16(W + (size_t)(n0 + row) * DIMN + k0 + sch * 8,
                        (char*)&Bsm[buf][0] + jj * 4096 + wid * 1024);
        }
    };

    stageA(0, 0); stageB(0, 0);
    int cur = 0;
    for (int t = 0; t < 32; t++) {
        if (t + 1 < 32) {
            stageA(cur ^ 1, (t + 1) * 32); stageB(cur ^ 1, (t + 1) * 32);
            if constexpr ((BMM / 64 + 2) == 3)
                asm volatile("s_waitcnt vmcnt(3)" ::: "memory");
            else
                asm volatile("s_waitcnt vmcnt(4)" ::: "memory");
        } else {
            asm volatile("s_waitcnt vmcnt(0)" ::: "memory");
        }
        __builtin_amdgcn_s_barrier();        // cur's loads visible to all waves
        __builtin_amdgcn_sched_barrier(0);

        bf16x8 af[MR], bfr[4];
#pragma unroll
        for (int m = 0; m < MR; m++) {
            int row = wr + m * 16 + lrow;
            int ch = g ^ ((row >> 1) & 3);
            af[m] = *(const bf16x8*)&Asm[cur][row * 32 + ch * 8];
        }
#pragma unroll
        for (int n = 0; n < 4; n++) {
            int row = wc + n * 16 + lrow;
            int ch = g ^ ((row >> 1) & 3);
            bfr[n] = *(const bf16x8*)&Bsm[cur][row * 32 + ch * 8];
        }
#pragma unroll
        for (int m = 0; m < MR; m++)
#pragma unroll
            for (int n = 0; n < 4; n++)
                acc[m][n] = mfma16(af[m], bfr[n], acc[m][n]);

        __builtin_amdgcn_sched_barrier(0);
        __builtin_amdgcn_s_barrier();        // readers done before next overwrite
        cur ^= 1;
    }

    const int rbase = g * 4;
#pragma unroll
    for (int m = 0; m < MR; m++) {
#pragma unroll
        for (int n = 0; n < 4; n++) {
            if (!OUT_F32 && vtmode) {
                // V^T fused write: 4 consecutive s (r=0..3) -> 4 consecutive
                // permuted positions p = gg*8 + t*4 + r  (byte-exact w/ vtrans)
                const int S0 = m0 + wr + m * 16 + rbase;       // global s, %4==0
                const int bb = S0 >> 11, sloc = S0 & 2047;
                const int scol = (sloc & ~31) + ((sloc >> 2) & 3) * 8 + ((sloc >> 4) & 1) * 4;
                const int col = n0 + wc + n * 16 + lrow;
                const int hh = col >> 6, dd = col & 63;
                ushort4 o4;
                o4.x = f2bf(acc[m][n][0]); o4.y = f2bf(acc[m][n][1]);
                o4.z = f2bf(acc[m][n][2]); o4.w = f2bf(acc[m][n][3]);
                *(ushort4*)((unsigned short*)Cv +
                            (size_t)((bb * HEADS + hh) * 64 + dd) * SEQ + scol) = o4;
            } else {
#pragma unroll
                for (int r = 0; r < 4; r++) {
                    int row = m0 + wr + m * 16 + rbase + r;
                    int col = n0 + wc + n * 16 + lrow;
                    float v = acc[m][n][r] * oscale;
                    if (BIAS) v += bias[col];
                    if (OUT_F32)
                        ((float*)Cv)[(size_t)row * DIMN + col] = v;
                    else
                        ((unsigned short*)Cv)[(size_t)row * DIMN + col] = f2bf(v);
                }
            }
        }
    }
}

// fused 3-projection GEMM (bf16 A); Q pre-scaled by 0.125*log2(e); V writes vt directly
__global__ __launch_bounds__(256, 3) void gemm_proj3_kernel(
    const unsigned short* __restrict__ A0, const unsigned short* __restrict__ A1,
    const unsigned short* __restrict__ A2,
    const unsigned short* __restrict__ W0, const unsigned short* __restrict__ W1,
    const unsigned short* __restrict__ W2,
    unsigned short* __restrict__ C0, unsigned short* __restrict__ C1,
    unsigned short* __restrict__ C2) {
    __shared__ unsigned short Asm[2][128 * 32];
    __shared__ unsigned short Bsm[2][128 * 32];
    const int z = blockIdx.z;
    const unsigned short* A = (z == 0) ? A0 : (z == 1) ? A1 : A2;
    const unsigned short* W = (z == 0) ? W0 : (z == 1) ? W1 : W2;
    unsigned short* C = (z == 0) ? C0 : (z == 1) ? C1 : C2;
    const float os = (z == 0) ? 0.18033688011112042f : 1.0f;
    gemm_core<128, false, false>(A, W, C, (const float*)nullptr, os, (z == 2) ? 1 : 0, Asm, Bsm);
}

__global__ __launch_bounds__(256, 2) void gemm_out_kernel(
    const unsigned short* __restrict__ A, const unsigned short* __restrict__ W,
    float* __restrict__ C, const float* __restrict__ bias) {
    __shared__ unsigned short AsmH[2][64 * 32];
    __shared__ unsigned short Bsm[2][128 * 32];
    gemm_core<64, true, true>(A, W, C, bias, 1.0f, 0, AsmH, Bsm);
}

// ---------------- attention tile compute (proven verbatim) ----------------
template<bool DIAG>
__device__ __forceinline__ void attn_tile(
    const unsigned short* __restrict__ Kc, const unsigned short* __restrict__ Vc,
    bf16x8 qf0, bf16x8 qf1, f32x4 (&o)[4], float& lrun,
    const int c, const int g, const int k0, const int qq) {
    float p[16];
    float rs = 0.f;
#pragma unroll
    for (int t = 0; t < 4; t++) {
        const int row = t * 16 + c;
        bf16x8 ka0 = *(const bf16x8*)&Kc[row * 64 + ((g ^ (c & 7)) * 8)];
        bf16x8 ka1 = *(const bf16x8*)&Kc[row * 64 + (((4 + g) ^ (c & 7)) * 8)];
        f32x4 s = mfma16(ka0, qf0, f32x4{0.f, 0.f, 0.f, 0.f});
        s = mfma16(ka1, qf1, s);
        const int kbase = k0 + t * 16 + 4 * g;
#pragma unroll
        for (int r = 0; r < 4; r++) {
            float pe = __builtin_exp2f(s[r]);
            if (DIAG && (kbase + r) > qq) pe = 0.f;
            p[t * 4 + r] = pe;
            rs += pe;
        }
    }
    rs += __shfl_xor(rs, 16);
    rs += __shfl_xor(rs, 32);
    lrun += rs;

    unsigned pk[8];
#pragma unroll
    for (int t = 0; t < 4; t++) {
        pk[t * 2 + 0] = cvtpk_bf16(p[t * 4 + 0], p[t * 4 + 1]);
        pk[t * 2 + 1] = cvtpk_bf16(p[t * 4 + 2], p[t * 4 + 3]);
    }
#pragma unroll
    for (int ks = 0; ks < 2; ks++) {
        union { unsigned u[4]; bf16x8 v; } pa;
        pa.u[0] = pk[4 * ks + 0]; pa.u[1] = pk[4 * ks + 1];
        pa.u[2] = pk[4 * ks + 2]; pa.u[3] = pk[4 * ks + 3];
#pragma unroll
        for (int dt = 0; dt < 4; dt++) {
            const int row = dt * 16 + c;
            bf16x8 vb = *(const bf16x8*)&Vc[row * 64 + ((((ks * 4) + g) ^ (c & 7)) * 8)];
            o[dt] = mfma16(pa.v, vb, o[dt]);
        }
    }
}

// ---------------- causal flash attention, paired q-tiles, 2-tiles-per-barrier [R15-passed verbatim] ----------------
__global__ __launch_bounds__(256, 2) void attn_kernel(
    const unsigned short* __restrict__ qp, const unsigned short* __restrict__ kp,
    const unsigned short* __restrict__ vt, unsigned short* __restrict__ ao) {
    const int tid = threadIdx.x, wid = tid >> 6, lane = tid & 63;
    const int c = lane & 15, g = lane >> 4;
    const int blk = blockIdx.x;            // 0..511
    const int kk = blk >> 3;               // 0..63
    const int bh = (blk & 7) + 8 * (kk >> 4);  // column -> XCD pin
    const int j = kk & 15;                 // pair index 0..15
    const int qA = j * 64;                 // light q-tile (j+1 kv tiles)
    const int qB = (31 - j) * 64;          // heavy q-tile (32-j kv tiles)
    const int b = bh >> 4, h = bh & 15;

    __shared__ unsigned short Kt[4][64 * 64];
    __shared__ unsigned short Vt[4][64 * 64];

    const unsigned short* qrowA = qp + (size_t)(b * SEQ + qA + wid * 16 + c) * DIMN + h * DK;
    bf16x8 qfA0 = *(const bf16x8*)(qrowA + g * 8);
    bf16x8 qfA1 = *(const bf16x8*)(qrowA + 32 + g * 8);
    const unsigned short* qrowB = qp + (size_t)(b * SEQ + qB + wid * 16 + c) * DIMN + h * DK;
    bf16x8 qfB0 = *(const bf16x8*)(qrowB + g * 8);
    bf16x8 qfB1 = *(const bf16x8*)(qrowB + 32 + g * 8);

    f32x4 oA[4], oB[4];
#pragma unroll
    for (int dt = 0; dt < 4; dt++) {
        oA[dt] = f32x4{0.f, 0.f, 0.f, 0.f};
        oB[dt] = f32x4{0.f, 0.f, 0.f, 0.f};
    }
    float lrunA = 0.f, lrunB = 0.f;

    const int nkt = 32 - j;                // kv tiles for B (>= 17); A uses 0..j
    const int qqA = qA + wid * 16 + c;
    const int qqB = qB + wid * 16 + c;

    auto stage = [&](int buf, int k0) {    // 4 loads/wave [proven verbatim]
#pragma unroll
        for (int jj = 0; jj < 2; jj++) {
            int boff = (jj * 4 + wid) * 1024;
            int off = boff + lane * 16;
            int row = off >> 7;
            int sch = ((off >> 4) & 7) ^ (row & 7);
            gload_lds16(kp + (size_t)(b * SEQ + k0 + row) * DIMN + h * DK + sch * 8,
                        (char*)&Kt[buf][0] + boff);
            gload_lds16(vt + (size_t)(bh * 64 + row) * SEQ + k0 + sch * 8,
                        (char*)&Vt[buf][0] + boff);
        }
    };

    // prologue: stage tiles 0..3 (nkt >= 17, all exist)
    stage(0, 0);
    stage(1, 64);
    stage(2, 128);
    stage(3, 192);

    for (int kt = 0; kt < nkt; kt += 2) {
        const int after = (kt + 4 <= nkt) ? 2 : (kt + 3 <= nkt) ? 1 : 0;
        if (after == 2)      asm volatile("s_waitcnt vmcnt(8)" ::: "memory");
        else if (after == 1) asm volatile("s_waitcnt vmcnt(4)" ::: "memory");
        else                 asm volatile("s_waitcnt vmcnt(0)" ::: "memory");
        __builtin_amdgcn_s_barrier();        // all waves' tiles kt,kt+1 visible
        __builtin_amdgcn_sched_barrier(0);

        for (int u = 0; u < 2; u++) {
            const int t = kt + u;
            if (t >= nkt) break;             // wave-uniform
            const int k0 = t * 64;
            const unsigned short* Kc = &Kt[t & 3][0];
            const unsigned short* Vc = &Vt[t & 3][0];

            if (t == nkt - 1)
                attn_tile<true>(Kc, Vc, qfB0, qfB1, oB, lrunB, c, g, k0, qqB);
            else
                attn_tile<false>(Kc, Vc, qfB0, qfB1, oB, lrunB, c, g, k0, qqB);

            if (t < j)
                attn_tile<false>(Kc, Vc, qfA0, qfA1, oA, lrunA, c, g, k0, qqA);
            else if (t == j)
                attn_tile<true>(Kc, Vc, qfA0, qfA1, oA, lrunA, c, g, k0, qqA);
        }

        __builtin_amdgcn_sched_barrier(0);
        __builtin_amdgcn_s_barrier();        // readers done before buffer reuse
        if (kt + 4 < nkt) stage((kt + 4) & 3, (kt + 4) * 64);
        if (kt + 5 < nkt) stage((kt + 5) & 3, (kt + 5) * 64);
    }

    float lrA[4], lrB[4];
#pragma unroll
    for (int r = 0; r < 4; r++) {
        lrA[r] = 1.0f / __shfl(lrunA, 4 * g + r);
        lrB[r] = 1.0f / __shfl(lrunB, 4 * g + r);
    }
#pragma unroll
    for (int dt = 0; dt < 4; dt++)
#pragma unroll
        for (int r = 0; r < 4; r++) {
            ao[(size_t)(b * SEQ + qA + wid * 16 + 4 * g + r) * DIMN + h * DK + dt * 16 + c] =
                f2bf(oA[dt][r] * lrA[r]);
            ao[(size_t)(b * SEQ + qB + wid * 16 + 4 * g + r) * DIMN + h * DK + dt * 16 + c] =
                f2bf(oB[dt][r] * lrB[r]);
        }
}

// ---------------- launch ----------------
extern "C" void kernel_launch(void* const* d_in, const int* in_sizes, int n_in,
                              void* d_out, int out_size, void* d_ws, size_t ws_size,
                              hipStream_t stream) {
    const float* Q  = (const float*)d_in[0];
    const float* K  = (const float*)d_in[1];
    const float* V  = (const float*)d_in[2];
    const float* wq = (const float*)d_in[4];
    const float* wk = (const float*)d_in[5];
    const float* wv = (const float*)d_in[6];
    const float* wo = (const float*)d_in[7];
    const float* wob = (const float*)d_in[8];

    char* ws = (char*)d_ws;
    const size_t SZ_ACT = (size_t)MROWS * DIMN * 2;  // 8MB
    const size_t SZ_W   = (size_t)DIMN * DIMN * 2;   // 2MB
    unsigned short* Qb  = (unsigned short*)(ws);
    unsigned short* Kb  = (unsigned short*)(ws + SZ_ACT);
    unsigned short* Vb  = (unsigned short*)(ws + 2 * SZ_ACT);
    unsigned short* Wqb = (unsigned short*)(ws + 3 * SZ_ACT);
    unsigned short* Wkb = (unsigned short*)(ws + 3 * SZ_ACT + SZ_W);
    unsigned short* Wvb = (unsigned short*)(ws + 3 * SZ_ACT + 2 * SZ_W);
    unsigned short* Wob = (unsigned short*)(ws + 3 * SZ_ACT + 3 * SZ_W);
    unsigned short* qp  = (unsigned short*)(ws + 3 * SZ_ACT + 4 * SZ_W);
    unsigned short* kp  = (unsigned short*)(ws + 4 * SZ_ACT + 4 * SZ_W);
    unsigned short* vt  = (unsigned short*)(ws + 5 * SZ_ACT + 4 * SZ_W);  // V^T (written by proj3 z=2)
    unsigned short* aob = Qb;   // alias: Qb dead after Q projection

    cvt_all_kernel<<<16384, 256, 0, stream>>>(Q, K, V, wq, wk, wv, wo,
                                              Qb, Kb, Vb, Wqb, Wkb, Wvb, Wob);

    dim3 gp(MROWS / 128, DIMN / 128, 3);
    gemm_proj3_kernel<<<gp, 256, 0, stream>>>(Qb, Kb, Vb, Wqb, Wkb, Wvb, qp, kp, vt);

    attn_kernel<<<512, 256, 0, stream>>>(qp, kp, vt, aob);

    dim3 go(MROWS / 64, DIMN / 128);
    gemm_out_kernel<<<go, 256, 0, stream>>>(aob, Wob, (float*)d_out, wob);
}

// Round 17
// 119.420 us; speedup vs baseline: 1.1671x; 1.0027x over previous
//
#include <hip/hip_runtime.h>

#define DIMN 1024
#define HEADS 16
#define DK 64
#define BATCH 2
#define SEQ 2048
#define MROWS (BATCH*SEQ)

typedef __bf16 bf16x8 __attribute__((ext_vector_type(8)));
typedef float f32x4 __attribute__((ext_vector_type(4)));

__device__ __forceinline__ unsigned short f2bf(float f) {
    unsigned int u = __float_as_uint(f);
    u += 0x7FFFu + ((u >> 16) & 1u);
    return (unsigned short)(u >> 16);
}

__device__ __forceinline__ f32x4 mfma16(bf16x8 a, bf16x8 b, f32x4 c) {
    return __builtin_amdgcn_mfma_f32_16x16x32_bf16(a, b, c, 0, 0, 0);
}

__device__ __forceinline__ void gload_lds16(const void* g, void* l) {
    __builtin_amdgcn_global_load_lds(
        (const __attribute__((address_space(1))) unsigned int*)g,
        (__attribute__((address_space(3))) unsigned int*)l, 16, 0, 0);
}

__device__ __forceinline__ unsigned cvtpk_bf16(float lo, float hi) {
    unsigned r;
    asm("v_cvt_pk_bf16_f32 %0, %1, %2" : "=v"(r) : "v"(lo), "v"(hi));
    return r;
}

// ---------------- fused fp32 -> bf16 conversion (7 arrays, 1 launch) [R5/R12-proven] ----------------
__global__ __launch_bounds__(256) void cvt_all_kernel(
    const float* __restrict__ s0, const float* __restrict__ s1, const float* __restrict__ s2,
    const float* __restrict__ s3, const float* __restrict__ s4, const float* __restrict__ s5,
    const float* __restrict__ s6,
    unsigned short* __restrict__ d0, unsigned short* __restrict__ d1,
    unsigned short* __restrict__ d2, unsigned short* __restrict__ d3,
    unsigned short* __restrict__ d4, unsigned short* __restrict__ d5,
    unsigned short* __restrict__ d6) {
    int bb = blockIdx.x;
    const float* src; unsigned short* dst; int base;
    if (bb < 12288) {
        int w = bb >> 12; base = bb & 4095;
        src = (w == 0) ? s0 : (w == 1) ? s1 : s2;
        dst = (w == 0) ? d0 : (w == 1) ? d1 : d2;
    } else {
        int w = (bb - 12288) >> 10; base = bb & 1023;
        src = (w == 0) ? s3 : (w == 1) ? s4 : (w == 2) ? s5 : s6;
        dst = (w == 0) ? d3 : (w == 1) ? d4 : (w == 2) ? d5 : d6;
    }
    int i = (base * 256 + threadIdx.x) * 4;
    float4 v = *reinterpret_cast<const float4*>(src + i);
    ushort4 o;
    o.x = f2bf(v.x); o.y = f2bf(v.y); o.z = f2bf(v.z); o.w = f2bf(v.w);
    *reinterpret_cast<ushort4*>(dst + i) = o;
}

// ---------------- GEMM core: C = A @ W^T (+bias), bf16, BN=128, BK=32 ----------------
// LDS XOR-swizzled both-sides [R8/R9-proven]; counted-vmcnt 2-phase loop [R11/R12-proven].
// vtmode (runtime, epilogue-only): write C in the attention V^T layout [R16-proven].
template<int BMM, bool OUT_F32, bool BIAS>
__device__ __forceinline__ void gemm_core(
    const unsigned short* __restrict__ A, const unsigned short* __restrict__ W,
    void* __restrict__ Cv, const float* __restrict__ bias, float oscale, int vtmode,
    unsigned short (&Asm)[2][BMM * 32], unsigned short (&Bsm)[2][128 * 32]) {
    const int tid = threadIdx.x, wid = tid >> 6, lane = tid & 63;
    const int m0 = blockIdx.x * BMM, n0 = blockIdx.y * 128;
    constexpr int MR = BMM / 32;
    const int wr = (wid >> 1) * (BMM / 2), wc = (wid & 1) * 64;
    const int lrow = lane & 15, g = lane >> 4;

    f32x4 acc[MR][4];
#pragma unroll
    for (int m = 0; m < MR; m++)
#pragma unroll
        for (int n = 0; n < 4; n++) acc[m][n] = f32x4{0.f, 0.f, 0.f, 0.f};

    auto stageA = [&](int buf, int k0) {
#pragma unroll
        for (int jj = 0; jj < BMM / 64; jj++) {
            int off = jj * 4096 + wid * 1024 + lane * 16;
            int row = off >> 6;                       // 64B rows (32 bf16)
            int sch = ((off >> 4) & 3) ^ ((row >> 1) & 3);
            gload_lds16(A + (size_t)(m0 + row) * DIMN + k0 + sch * 8,
                        (char*)&Asm[buf][0] + jj * 4096 + wid * 1024);
        }
    };
    auto stageB = [&](int buf, int k0) {
#pragma unroll
        for (int jj = 0; jj < 2; jj++) {
            int off = jj * 4096 + wid * 1024 + lane * 16;
            int row = off >> 6;
            int sch = ((off >> 4) & 3) ^ ((row >> 1) & 3);
            gload_lds16(W + (size_t)(n0 + row) * DIMN + k0 + sch * 8,
                        (char*)&Bsm[buf][0] + jj * 4096 + wid * 1024);
        }
    };

    stageA(0, 0); stageB(0, 0);
    int cur = 0;
    for (int t = 0; t < 32; t++) {
        if (t + 1 < 32) {
            stageA(cur ^ 1, (t + 1) * 32); stageB(cur ^ 1, (t + 1) * 32);
            if constexpr ((BMM / 64 + 2) == 3)
                asm volatile("s_waitcnt vmcnt(3)" ::: "memory");
            else
                asm volatile("s_waitcnt vmcnt(4)" ::: "memory");
        } else {
            asm volatile("s_waitcnt vmcnt(0)" ::: "memory");
        }
        __builtin_amdgcn_s_barrier();        // cur's loads visible to all waves
        __builtin_amdgcn_sched_barrier(0);

        bf16x8 af[MR], bfr[4];
#pragma unroll
        for (int m = 0; m < MR; m++) {
            int row = wr + m * 16 + lrow;
            int ch = g ^ ((row >> 1) & 3);
            af[m] = *(const bf16x8*)&Asm[cur][row * 32 + ch * 8];
        }
#pragma unroll
        for (int n = 0; n < 4; n++) {
            int row = wc + n * 16 + lrow;
            int ch = g ^ ((row >> 1) & 3);
            bfr[n] = *(const bf16x8*)&Bsm[cur][row * 32 + ch * 8];
        }
#pragma unroll
        for (int m = 0; m < MR; m++)
#pragma unroll
            for (int n = 0; n < 4; n++)
                acc[m][n] = mfma16(af[m], bfr[n], acc[m][n]);

        __builtin_amdgcn_sched_barrier(0);
        __builtin_amdgcn_s_barrier();        // readers done before next overwrite
        cur ^= 1;
    }

    const int rbase = g * 4;
#pragma unroll
    for (int m = 0; m < MR; m++) {
#pragma unroll
        for (int n = 0; n < 4; n++) {
            if (!OUT_F32 && vtmode) {
                // V^T fused write [R16-proven byte-exact with vtrans]
                const int S0 = m0 + wr + m * 16 + rbase;       // global s, %4==0
                const int bb = S0 >> 11, sloc = S0 & 2047;
                const int scol = (sloc & ~31) + ((sloc >> 2) & 3) * 8 + ((sloc >> 4) & 1) * 4;
                const int col = n0 + wc + n * 16 + lrow;
                const int hh = col >> 6, dd = col & 63;
                ushort4 o4;
                o4.x = f2bf(acc[m][n][0]); o4.y = f2bf(acc[m][n][1]);
                o4.z = f2bf(acc[m][n][2]); o4.w = f2bf(acc[m][n][3]);
                *(ushort4*)((unsigned short*)Cv +
                            (size_t)((bb * HEADS + hh) * 64 + dd) * SEQ + scol) = o4;
            } else {
#pragma unroll
                for (int r = 0; r < 4; r++) {
                    int row = m0 + wr + m * 16 + rbase + r;
                    int col = n0 + wc + n * 16 + lrow;
                    float v = acc[m][n][r] * oscale;
                    if (BIAS) v += bias[col];
                    if (OUT_F32)
                        ((float*)Cv)[(size_t)row * DIMN + col] = v;
                    else
                        ((unsigned short*)Cv)[(size_t)row * DIMN + col] = f2bf(v);
                }
            }
        }
    }
}

// fused 3-projection GEMM (bf16 A); Q pre-scaled by 0.125*log2(e); V writes vt directly
__global__ __launch_bounds__(256, 3) void gemm_proj3_kernel(
    const unsigned short* __restrict__ A0, const unsigned short* __restrict__ A1,
    const unsigned short* __restrict__ A2,
    const unsigned short* __restrict__ W0, const unsigned short* __restrict__ W1,
    const unsigned short* __restrict__ W2,
    unsigned short* __restrict__ C0, unsigned short* __restrict__ C1,
    unsigned short* __restrict__ C2) {
    __shared__ unsigned short Asm[2][128 * 32];
    __shared__ unsigned short Bsm[2][128 * 32];
    const int z = blockIdx.z;
    const unsigned short* A = (z == 0) ? A0 : (z == 1) ? A1 : A2;
    const unsigned short* W = (z == 0) ? W0 : (z == 1) ? W1 : W2;
    unsigned short* C = (z == 0) ? C0 : (z == 1) ? C1 : C2;
    const float os = (z == 0) ? 0.18033688011112042f : 1.0f;
    gemm_core<128, false, false>(A, W, C, (const float*)nullptr, os, (z == 2) ? 1 : 0, Asm, Bsm);
}

__global__ __launch_bounds__(256, 2) void gemm_out_kernel(
    const unsigned short* __restrict__ A, const unsigned short* __restrict__ W,
    float* __restrict__ C, const float* __restrict__ bias) {
    __shared__ unsigned short AsmH[2][64 * 32];
    __shared__ unsigned short Bsm[2][128 * 32];
    gemm_core<64, true, true>(A, W, C, bias, 1.0f, 0, AsmH, Bsm);
}

// ---------------- attention tile compute ----------------
// R16-proven math; softmax sum restructured as 4 independent partial chains
// (no -ffast-math reassociation -> hand-tree the 16-deep serial add chain).
template<bool DIAG>
__device__ __forceinline__ void attn_tile(
    const unsigned short* __restrict__ Kc, const unsigned short* __restrict__ Vc,
    bf16x8 qf0, bf16x8 qf1, f32x4 (&o)[4], float& lrun,
    const int c, const int g, const int k0, const int qq) {
    float p[16];
    float rsp[4];
#pragma unroll
    for (int t = 0; t < 4; t++) {
        const int row = t * 16 + c;
        bf16x8 ka0 = *(const bf16x8*)&Kc[row * 64 + ((g ^ (c & 7)) * 8)];
        bf16x8 ka1 = *(const bf16x8*)&Kc[row * 64 + (((4 + g) ^ (c & 7)) * 8)];
        f32x4 s = mfma16(ka0, qf0, f32x4{0.f, 0.f, 0.f, 0.f});
        s = mfma16(ka1, qf1, s);
        const int kbase = k0 + t * 16 + 4 * g;
        float acc0 = 0.f, acc1 = 0.f;
#pragma unroll
        for (int r = 0; r < 4; r++) {
            float pe = __builtin_exp2f(s[r]);
            if (DIAG && (kbase + r) > qq) pe = 0.f;
            p[t * 4 + r] = pe;
            if (r & 1) acc1 += pe; else acc0 += pe;
        }
        rsp[t] = acc0 + acc1;
    }
    float rs = (rsp[0] + rsp[1]) + (rsp[2] + rsp[3]);
    rs += __shfl_xor(rs, 16);
    rs += __shfl_xor(rs, 32);
    lrun += rs;

    unsigned pk[8];
#pragma unroll
    for (int t = 0; t < 4; t++) {
        pk[t * 2 + 0] = cvtpk_bf16(p[t * 4 + 0], p[t * 4 + 1]);
        pk[t * 2 + 1] = cvtpk_bf16(p[t * 4 + 2], p[t * 4 + 3]);
    }
#pragma unroll
    for (int ks = 0; ks < 2; ks++) {
        union { unsigned u[4]; bf16x8 v; } pa;
        pa.u[0] = pk[4 * ks + 0]; pa.u[1] = pk[4 * ks + 1];
        pa.u[2] = pk[4 * ks + 2]; pa.u[3] = pk[4 * ks + 3];
#pragma unroll
        for (int dt = 0; dt < 4; dt++) {
            const int row = dt * 16 + c;
            bf16x8 vb = *(const bf16x8*)&Vc[row * 64 + ((((ks * 4) + g) ^ (c & 7)) * 8)];
            o[dt] = mfma16(pa.v, vb, o[dt]);
        }
    }
}

// ---------------- causal flash attention, paired q-tiles, 2-tiles-per-barrier [R15/R16-passed] ----------------
__global__ __launch_bounds__(256, 2) void attn_kernel(
    const unsigned short* __restrict__ qp, const unsigned short* __restrict__ kp,
    const unsigned short* __restrict__ vt, unsigned short* __restrict__ ao) {
    const int tid = threadIdx.x, wid = tid >> 6, lane = tid & 63;
    const int c = lane & 15, g = lane >> 4;
    const int blk = blockIdx.x;            // 0..511
    const int kk = blk >> 3;               // 0..63
    const int bh = (blk & 7) + 8 * (kk >> 4);  // column -> XCD pin
    const int j = kk & 15;                 // pair index 0..15
    const int qA = j * 64;                 // light q-tile (j+1 kv tiles)
    const int qB = (31 - j) * 64;          // heavy q-tile (32-j kv tiles)
    const int b = bh >> 4, h = bh & 15;

    __shared__ unsigned short Kt[4][64 * 64];
    __shared__ unsigned short Vt[4][64 * 64];

    const unsigned short* qrowA = qp + (size_t)(b * SEQ + qA + wid * 16 + c) * DIMN + h * DK;
    bf16x8 qfA0 = *(const bf16x8*)(qrowA + g * 8);
    bf16x8 qfA1 = *(const bf16x8*)(qrowA + 32 + g * 8);
    const unsigned short* qrowB = qp + (size_t)(b * SEQ + qB + wid * 16 + c) * DIMN + h * DK;
    bf16x8 qfB0 = *(const bf16x8*)(qrowB + g * 8);
    bf16x8 qfB1 = *(const bf16x8*)(qrowB + 32 + g * 8);

    f32x4 oA[4], oB[4];
#pragma unroll
    for (int dt = 0; dt < 4; dt++) {
        oA[dt] = f32x4{0.f, 0.f, 0.f, 0.f};
        oB[dt] = f32x4{0.f, 0.f, 0.f, 0.f};
    }
    float lrunA = 0.f, lrunB = 0.f;

    const int nkt = 32 - j;                // kv tiles for B (>= 17); A uses 0..j
    const int qqA = qA + wid * 16 + c;
    const int qqB = qB + wid * 16 + c;

    auto stage = [&](int buf, int k0) {    // 4 loads/wave [proven verbatim]
#pragma unroll
        for (int jj = 0; jj < 2; jj++) {
            int boff = (jj * 4 + wid) * 1024;
            int off = boff + lane * 16;
            int row = off >> 7;
            int sch = ((off >> 4) & 7) ^ (row & 7);
            gload_lds16(kp + (size_t)(b * SEQ + k0 + row) * DIMN + h * DK + sch * 8,
                        (char*)&Kt[buf][0] + boff);
            gload_lds16(vt + (size_t)(bh * 64 + row) * SEQ + k0 + sch * 8,
                        (char*)&Vt[buf][0] + boff);
        }
    };

    // prologue: stage tiles 0..3 (nkt >= 17, all exist)
    stage(0, 0);
    stage(1, 64);
    stage(2, 128);
    stage(3, 192);

    for (int kt = 0; kt < nkt; kt += 2) {
        const int after = (kt + 4 <= nkt) ? 2 : (kt + 3 <= nkt) ? 1 : 0;
        if (after == 2)      asm volatile("s_waitcnt vmcnt(8)" ::: "memory");
        else if (after == 1) asm volatile("s_waitcnt vmcnt(4)" ::: "memory");
        else                 asm volatile("s_waitcnt vmcnt(0)" ::: "memory");
        __builtin_amdgcn_s_barrier();        // all waves' tiles kt,kt+1 visible
        __builtin_amdgcn_sched_barrier(0);

        for (int u = 0; u < 2; u++) {
            const int t = kt + u;
            if (t >= nkt) break;             // wave-uniform
            const int k0 = t * 64;
            const unsigned short* Kc = &Kt[t & 3][0];
            const unsigned short* Vc = &Vt[t & 3][0];

            if (t == nkt - 1)
                attn_tile<true>(Kc, Vc, qfB0, qfB1, oB, lrunB, c, g, k0, qqB);
            else
                attn_tile<false>(Kc, Vc, qfB0, qfB1, oB, lrunB, c, g, k0, qqB);

            if (t < j)
                attn_tile<false>(Kc, Vc, qfA0, qfA1, oA, lrunA, c, g, k0, qqA);
            else if (t == j)
                attn_tile<true>(Kc, Vc, qfA0, qfA1, oA, lrunA, c, g, k0, qqA);
        }

        __builtin_amdgcn_sched_barrier(0);
        __builtin_amdgcn_s_barrier();        // readers done before buffer reuse
        if (kt + 4 < nkt) stage((kt + 4) & 3, (kt + 4) * 64);
        if (kt + 5 < nkt) stage((kt + 5) & 3, (kt + 5) * 64);
    }

    float lrA[4], lrB[4];
#pragma unroll
    for (int r = 0; r < 4; r++) {
        lrA[r] = 1.0f / __shfl(lrunA, 4 * g + r);
        lrB[r] = 1.0f / __shfl(lrunB, 4 * g + r);
    }
#pragma unroll
    for (int dt = 0; dt < 4; dt++)
#pragma unroll
        for (int r = 0; r < 4; r++) {
            ao[(size_t)(b * SEQ + qA + wid * 16 + 4 * g + r) * DIMN + h * DK + dt * 16 + c] =
                f2bf(oA[dt][r] * lrA[r]);
            ao[(size_t)(b * SEQ + qB + wid * 16 + 4 * g + r) * DIMN + h * DK + dt * 16 + c] =
                f2bf(oB[dt][r] * lrB[r]);
        }
}

// ---------------- launch ----------------
extern "C" void kernel_launch(void* const* d_in, const int* in_sizes, int n_in,
                              void* d_out, int out_size, void* d_ws, size_t ws_size,
                              hipStream_t stream) {
    const float* Q  = (const float*)d_in[0];
    const float* K  = (const float*)d_in[1];
    const float* V  = (const float*)d_in[2];
    const float* wq = (const float*)d_in[4];
    const float* wk = (const float*)d_in[5];
    const float* wv = (const float*)d_in[6];
    const float* wo = (const float*)d_in[7];
    const float* wob = (const float*)d_in[8];

    char* ws = (char*)d_ws;
    const size_t SZ_ACT = (size_t)MROWS * DIMN * 2;  // 8MB
    const size_t SZ_W   = (size_t)DIMN * DIMN * 2;   // 2MB
    unsigned short* Qb  = (unsigned short*)(ws);
    unsigned short* Kb  = (unsigned short*)(ws + SZ_ACT);
    unsigned short* Vb  = (unsigned short*)(ws + 2 * SZ_ACT);
    unsigned short* Wqb = (unsigned short*)(ws + 3 * SZ_ACT);
    unsigned short* Wkb = (unsigned short*)(ws + 3 * SZ_ACT + SZ_W);
    unsigned short* Wvb = (unsigned short*)(ws + 3 * SZ_ACT + 2 * SZ_W);
    unsigned short* Wob = (unsigned short*)(ws + 3 * SZ_ACT + 3 * SZ_W);
    unsigned short* qp  = (unsigned short*)(ws + 3 * SZ_ACT + 4 * SZ_W);
    unsigned short* kp  = (unsigned short*)(ws + 4 * SZ_ACT + 4 * SZ_W);
    unsigned short* vt  = (unsigned short*)(ws + 5 * SZ_ACT + 4 * SZ_W);  // V^T (proj3 z=2)
    unsigned short* aob = Qb;   // alias: Qb dead after Q projection

    cvt_all_kernel<<<16384, 256, 0, stream>>>(Q, K, V, wq, wk, wv, wo,
                                              Qb, Kb, Vb, Wqb, Wkb, Wvb, Wob);

    dim3 gp(MROWS / 128, DIMN / 128, 3);
    gemm_proj3_kernel<<<gp, 256, 0, stream>>>(Qb, Kb, Vb, Wqb, Wkb, Wvb, qp, kp, vt);

    attn_kernel<<<512, 256, 0, stream>>>(qp, kp, vt, aob);

    dim3 go(MROWS / 64, DIMN / 128);
    gemm_out_kernel<<<go, 256, 0, stream>>>(aob, Wob, (float*)d_out, wob);
}

// Round 18
// 119.188 us; speedup vs baseline: 1.1694x; 1.0020x over previous
//
#include <hip/hip_runtime.h>

#define DIMN 1024
#define HEADS 16
#define DK 64
#define BATCH 2
#define SEQ 2048
#define MROWS (BATCH*SEQ)

typedef __bf16 bf16x8 __attribute__((ext_vector_type(8)));
typedef float f32x4 __attribute__((ext_vector_type(4)));

__device__ __forceinline__ unsigned short f2bf(float f) {
    unsigned int u = __float_as_uint(f);
    u += 0x7FFFu + ((u >> 16) & 1u);
    return (unsigned short)(u >> 16);
}

__device__ __forceinline__ f32x4 mfma16(bf16x8 a, bf16x8 b, f32x4 c) {
    return __builtin_amdgcn_mfma_f32_16x16x32_bf16(a, b, c, 0, 0, 0);
}

__device__ __forceinline__ void gload_lds16(const void* g, void* l) {
    __builtin_amdgcn_global_load_lds(
        (const __attribute__((address_space(1))) unsigned int*)g,
        (__attribute__((address_space(3))) unsigned int*)l, 16, 0, 0);
}

__device__ __forceinline__ unsigned cvtpk_bf16(float lo, float hi) {
    unsigned r;
    asm("v_cvt_pk_bf16_f32 %0, %1, %2" : "=v"(r) : "v"(lo), "v"(hi));
    return r;
}

// ---------------- fused fp32 -> bf16 conversion (7 arrays, 1 launch) [R5/R12-proven] ----------------
__global__ __launch_bounds__(256) void cvt_all_kernel(
    const float* __restrict__ s0, const float* __restrict__ s1, const float* __restrict__ s2,
    const float* __restrict__ s3, const float* __restrict__ s4, const float* __restrict__ s5,
    const float* __restrict__ s6,
    unsigned short* __restrict__ d0, unsigned short* __restrict__ d1,
    unsigned short* __restrict__ d2, unsigned short* __restrict__ d3,
    unsigned short* __restrict__ d4, unsigned short* __restrict__ d5,
    unsigned short* __restrict__ d6) {
    int bb = blockIdx.x;
    const float* src; unsigned short* dst; int base;
    if (bb < 12288) {
        int w = bb >> 12; base = bb & 4095;
        src = (w == 0) ? s0 : (w == 1) ? s1 : s2;
        dst = (w == 0) ? d0 : (w == 1) ? d1 : d2;
    } else {
        int w = (bb - 12288) >> 10; base = bb & 1023;
        src = (w == 0) ? s3 : (w == 1) ? s4 : (w == 2) ? s5 : s6;
        dst = (w == 0) ? d3 : (w == 1) ? d4 : (w == 2) ? d5 : d6;
    }
    int i = (base * 256 + threadIdx.x) * 4;
    float4 v = *reinterpret_cast<const float4*>(src + i);
    ushort4 o;
    o.x = f2bf(v.x); o.y = f2bf(v.y); o.z = f2bf(v.z); o.w = f2bf(v.w);
    *reinterpret_cast<ushort4*>(dst + i) = o;
}

// ---------------- GEMM core: C = A @ W^T (+bias), bf16, BN=128, BK=32 ----------------
// LDS XOR-swizzled both-sides [R8/R9-proven]; counted-vmcnt 2-phase loop [R11/R12-proven].
// vtmode (runtime, epilogue-only): write C in the attention V^T layout [R16-proven].
template<int BMM, bool OUT_F32, bool BIAS>
__device__ __forceinline__ void gemm_core(
    const unsigned short* __restrict__ A, const unsigned short* __restrict__ W,
    void* __restrict__ Cv, const float* __restrict__ bias, float oscale, int vtmode,
    unsigned short (&Asm)[2][BMM * 32], unsigned short (&Bsm)[2][128 * 32]) {
    const int tid = threadIdx.x, wid = tid >> 6, lane = tid & 63;
    const int m0 = blockIdx.x * BMM, n0 = blockIdx.y * 128;
    constexpr int MR = BMM / 32;
    const int wr = (wid >> 1) * (BMM / 2), wc = (wid & 1) * 64;
    const int lrow = lane & 15, g = lane >> 4;

    f32x4 acc[MR][4];
#pragma unroll
    for (int m = 0; m < MR; m++)
#pragma unroll
        for (int n = 0; n < 4; n++) acc[m][n] = f32x4{0.f, 0.f, 0.f, 0.f};

    auto stageA = [&](int buf, int k0) {
#pragma unroll
        for (int jj = 0; jj < BMM / 64; jj++) {
            int off = jj * 4096 + wid * 1024 + lane * 16;
            int row = off >> 6;                       // 64B rows (32 bf16)
            int sch = ((off >> 4) & 3) ^ ((row >> 1) & 3);
            gload_lds16(A + (size_t)(m0 + row) * DIMN + k0 + sch * 8,
                        (char*)&Asm[buf][0] + jj * 4096 + wid * 1024);
        }
    };
    auto stageB = [&](int buf, int k0) {
#pragma unroll
        for (int jj = 0; jj < 2; jj++) {
            int off = jj * 4096 + wid * 1024 + lane * 16;
            int row = off >> 6;
            int sch = ((off >> 4) & 3) ^ ((row >> 1) & 3);
            gload_lds16(W + (size_t)(n0 + row) * DIMN + k0 + sch * 8,
                        (char*)&Bsm[buf][0] + jj * 4096 + wid * 1024);
        }
    };

    stageA(0, 0); stageB(0, 0);
    int cur = 0;
    for (int t = 0; t < 32; t++) {
        if (t + 1 < 32) {
            stageA(cur ^ 1, (t + 1) * 32); stageB(cur ^ 1, (t + 1) * 32);
            if constexpr ((BMM / 64 + 2) == 3)
                asm volatile("s_waitcnt vmcnt(3)" ::: "memory");
            else
                asm volatile("s_waitcnt vmcnt(4)" ::: "memory");
        } else {
            asm volatile("s_waitcnt vmcnt(0)" ::: "memory");
        }
        __builtin_amdgcn_s_barrier();        // cur's loads visible to all waves
        __builtin_amdgcn_sched_barrier(0);

        bf16x8 af[MR], bfr[4];
#pragma unroll
        for (int m = 0; m < MR; m++) {
            int row = wr + m * 16 + lrow;
            int ch = g ^ ((row >> 1) & 3);
            af[m] = *(const bf16x8*)&Asm[cur][row * 32 + ch * 8];
        }
#pragma unroll
        for (int n = 0; n < 4; n++) {
            int row = wc + n * 16 + lrow;
            int ch = g ^ ((row >> 1) & 3);
            bfr[n] = *(const bf16x8*)&Bsm[cur][row * 32 + ch * 8];
        }
#pragma unroll
        for (int m = 0; m < MR; m++)
#pragma unroll
            for (int n = 0; n < 4; n++)
                acc[m][n] = mfma16(af[m], bfr[n], acc[m][n]);

        __builtin_amdgcn_sched_barrier(0);
        __builtin_amdgcn_s_barrier();        // readers done before next overwrite
        cur ^= 1;
    }

    const int rbase = g * 4;
#pragma unroll
    for (int m = 0; m < MR; m++) {
#pragma unroll
        for (int n = 0; n < 4; n++) {
            if (!OUT_F32 && vtmode) {
                // V^T fused write [R16-proven byte-exact with vtrans]
                const int S0 = m0 + wr + m * 16 + rbase;       // global s, %4==0
                const int bb = S0 >> 11, sloc = S0 & 2047;
                const int scol = (sloc & ~31) + ((sloc >> 2) & 3) * 8 + ((sloc >> 4) & 1) * 4;
                const int col = n0 + wc + n * 16 + lrow;
                const int hh = col >> 6, dd = col & 63;
                ushort4 o4;
                o4.x = f2bf(acc[m][n][0]); o4.y = f2bf(acc[m][n][1]);
                o4.z = f2bf(acc[m][n][2]); o4.w = f2bf(acc[m][n][3]);
                *(ushort4*)((unsigned short*)Cv +
                            (size_t)((bb * HEADS + hh) * 64 + dd) * SEQ + scol) = o4;
            } else {
#pragma unroll
                for (int r = 0; r < 4; r++) {
                    int row = m0 + wr + m * 16 + rbase + r;
                    int col = n0 + wc + n * 16 + lrow;
                    float v = acc[m][n][r] * oscale;
                    if (BIAS) v += bias[col];
                    if (OUT_F32)
                        ((float*)Cv)[(size_t)row * DIMN + col] = v;
                    else
                        ((unsigned short*)Cv)[(size_t)row * DIMN + col] = f2bf(v);
                }
            }
        }
    }
}

// fused 3-projection GEMM (bf16 A); Q pre-scaled by 0.125*log2(e); V writes vt directly
__global__ __launch_bounds__(256, 3) void gemm_proj3_kernel(
    const unsigned short* __restrict__ A0, const unsigned short* __restrict__ A1,
    const unsigned short* __restrict__ A2,
    const unsigned short* __restrict__ W0, const unsigned short* __restrict__ W1,
    const unsigned short* __restrict__ W2,
    unsigned short* __restrict__ C0, unsigned short* __restrict__ C1,
    unsigned short* __restrict__ C2) {
    __shared__ unsigned short Asm[2][128 * 32];
    __shared__ unsigned short Bsm[2][128 * 32];
    const int z = blockIdx.z;
    const unsigned short* A = (z == 0) ? A0 : (z == 1) ? A1 : A2;
    const unsigned short* W = (z == 0) ? W0 : (z == 1) ? W1 : W2;
    unsigned short* C = (z == 0) ? C0 : (z == 1) ? C1 : C2;
    const float os = (z == 0) ? 0.18033688011112042f : 1.0f;
    gemm_core<128, false, false>(A, W, C, (const float*)nullptr, os, (z == 2) ? 1 : 0, Asm, Bsm);
}

__global__ __launch_bounds__(256, 3) void gemm_out_kernel(
    const unsigned short* __restrict__ A, const unsigned short* __restrict__ W,
    float* __restrict__ C, const float* __restrict__ bias) {
    __shared__ unsigned short AsmH[2][64 * 32];
    __shared__ unsigned short Bsm[2][128 * 32];
    gemm_core<64, true, true>(A, W, C, bias, 1.0f, 0, AsmH, Bsm);
}

// ---------------- attention tile compute [R16/R17-proven] ----------------
template<bool DIAG>
__device__ __forceinline__ void attn_tile(
    const unsigned short* __restrict__ Kc, const unsigned short* __restrict__ Vc,
    bf16x8 qf0, bf16x8 qf1, f32x4 (&o)[4], float& lrun,
    const int c, const int g, const int k0, const int qq) {
    float p[16];
    float rsp[4];
#pragma unroll
    for (int t = 0; t < 4; t++) {
        const int row = t * 16 + c;
        bf16x8 ka0 = *(const bf16x8*)&Kc[row * 64 + ((g ^ (c & 7)) * 8)];
        bf16x8 ka1 = *(const bf16x8*)&Kc[row * 64 + (((4 + g) ^ (c & 7)) * 8)];
        f32x4 s = mfma16(ka0, qf0, f32x4{0.f, 0.f, 0.f, 0.f});
        s = mfma16(ka1, qf1, s);
        const int kbase = k0 + t * 16 + 4 * g;
        float acc0 = 0.f, acc1 = 0.f;
#pragma unroll
        for (int r = 0; r < 4; r++) {
            float pe = __builtin_exp2f(s[r]);
            if (DIAG && (kbase + r) > qq) pe = 0.f;
            p[t * 4 + r] = pe;
            if (r & 1) acc1 += pe; else acc0 += pe;
        }
        rsp[t] = acc0 + acc1;
    }
    float rs = (rsp[0] + rsp[1]) + (rsp[2] + rsp[3]);
    rs += __shfl_xor(rs, 16);
    rs += __shfl_xor(rs, 32);
    lrun += rs;

    unsigned pk[8];
#pragma unroll
    for (int t = 0; t < 4; t++) {
        pk[t * 2 + 0] = cvtpk_bf16(p[t * 4 + 0], p[t * 4 + 1]);
        pk[t * 2 + 1] = cvtpk_bf16(p[t * 4 + 2], p[t * 4 + 3]);
    }
#pragma unroll
    for (int ks = 0; ks < 2; ks++) {
        union { unsigned u[4]; bf16x8 v; } pa;
        pa.u[0] = pk[4 * ks + 0]; pa.u[1] = pk[4 * ks + 1];
        pa.u[2] = pk[4 * ks + 2]; pa.u[3] = pk[4 * ks + 3];
#pragma unroll
        for (int dt = 0; dt < 4; dt++) {
            const int row = dt * 16 + c;
            bf16x8 vb = *(const bf16x8*)&Vc[row * 64 + ((((ks * 4) + g) ^ (c & 7)) * 8)];
            o[dt] = mfma16(pa.v, vb, o[dt]);
        }
    }
}

// ---------------- causal flash attention, paired q-tiles, 2-tiles-per-barrier ----------------
// [R15/R16/R17-passed structure] + complementary-j CU pairing: the dispatcher
// fills each XCD's 32 CUs twice, so XCD-local blocks kk and kk+32 share a CU.
// Flipping j -> 15-j for kk>=32 gives every CU one heavy + one light block
// (uniform 25 barrier-intervals/CU instead of worst-case 32). Bijective per
// (bh, j); correctness independent of dispatch order.
__global__ __launch_bounds__(256, 2) void attn_kernel(
    const unsigned short* __restrict__ qp, const unsigned short* __restrict__ kp,
    const unsigned short* __restrict__ vt, unsigned short* __restrict__ ao) {
    const int tid = threadIdx.x, wid = tid >> 6, lane = tid & 63;
    const int c = lane & 15, g = lane >> 4;
    const int blk = blockIdx.x;            // 0..511
    const int kk = blk >> 3;               // 0..63 (XCD-local block index)
    const int bh = (blk & 7) + 8 * (kk >> 4);  // column -> XCD pin
    const int jr = kk & 15;
    const int j = (kk >> 5) ? (15 - jr) : jr;  // complementary pairing across CU passes
    const int qA = j * 64;                 // light q-tile (j+1 kv tiles)
    const int qB = (31 - j) * 64;          // heavy q-tile (32-j kv tiles)
    const int b = bh >> 4, h = bh & 15;

    __shared__ unsigned short Kt[4][64 * 64];
    __shared__ unsigned short Vt[4][64 * 64];

    const unsigned short* qrowA = qp + (size_t)(b * SEQ + qA + wid * 16 + c) * DIMN + h * DK;
    bf16x8 qfA0 = *(const bf16x8*)(qrowA + g * 8);
    bf16x8 qfA1 = *(const bf16x8*)(qrowA + 32 + g * 8);
    const unsigned short* qrowB = qp + (size_t)(b * SEQ + qB + wid * 16 + c) * DIMN + h * DK;
    bf16x8 qfB0 = *(const bf16x8*)(qrowB + g * 8);
    bf16x8 qfB1 = *(const bf16x8*)(qrowB + 32 + g * 8);

    f32x4 oA[4], oB[4];
#pragma unroll
    for (int dt = 0; dt < 4; dt++) {
        oA[dt] = f32x4{0.f, 0.f, 0.f, 0.f};
        oB[dt] = f32x4{0.f, 0.f, 0.f, 0.f};
    }
    float lrunA = 0.f, lrunB = 0.f;

    const int nkt = 32 - j;                // kv tiles for B (>= 17); A uses 0..j
    const int qqA = qA + wid * 16 + c;
    const int qqB = qB + wid * 16 + c;

    auto stage = [&](int buf, int k0) {    // 4 loads/wave [proven verbatim]
#pragma unroll
        for (int jj = 0; jj < 2; jj++) {
            int boff = (jj * 4 + wid) * 1024;
            int off = boff + lane * 16;
            int row = off >> 7;
            int sch = ((off >> 4) & 7) ^ (row & 7);
            gload_lds16(kp + (size_t)(b * SEQ + k0 + row) * DIMN + h * DK + sch * 8,
                        (char*)&Kt[buf][0] + boff);
            gload_lds16(vt + (size_t)(bh * 64 + row) * SEQ + k0 + sch * 8,
                        (char*)&Vt[buf][0] + boff);
        }
    };

    // prologue: stage tiles 0..3 (nkt >= 17, all exist)
    stage(0, 0);
    stage(1, 64);
    stage(2, 128);
    stage(3, 192);

    for (int kt = 0; kt < nkt; kt += 2) {
        const int after = (kt + 4 <= nkt) ? 2 : (kt + 3 <= nkt) ? 1 : 0;
        if (after == 2)      asm volatile("s_waitcnt vmcnt(8)" ::: "memory");
        else if (after == 1) asm volatile("s_waitcnt vmcnt(4)" ::: "memory");
        else                 asm volatile("s_waitcnt vmcnt(0)" ::: "memory");
        __builtin_amdgcn_s_barrier();        // all waves' tiles kt,kt+1 visible
        __builtin_amdgcn_sched_barrier(0);

        for (int u = 0; u < 2; u++) {
            const int t = kt + u;
            if (t >= nkt) break;             // wave-uniform
            const int k0 = t * 64;
            const unsigned short* Kc = &Kt[t & 3][0];
            const unsigned short* Vc = &Vt[t & 3][0];

            if (t == nkt - 1)
                attn_tile<true>(Kc, Vc, qfB0, qfB1, oB, lrunB, c, g, k0, qqB);
            else
                attn_tile<false>(Kc, Vc, qfB0, qfB1, oB, lrunB, c, g, k0, qqB);

            if (t < j)
                attn_tile<false>(Kc, Vc, qfA0, qfA1, oA, lrunA, c, g, k0, qqA);
            else if (t == j)
                attn_tile<true>(Kc, Vc, qfA0, qfA1, oA, lrunA, c, g, k0, qqA);
        }

        __builtin_amdgcn_sched_barrier(0);
        __builtin_amdgcn_s_barrier();        // readers done before buffer reuse
        if (kt + 4 < nkt) stage((kt + 4) & 3, (kt + 4) * 64);
        if (kt + 5 < nkt) stage((kt + 5) & 3, (kt + 5) * 64);
    }

    float lrA[4], lrB[4];
#pragma unroll
    for (int r = 0; r < 4; r++) {
        lrA[r] = 1.0f / __shfl(lrunA, 4 * g + r);
        lrB[r] = 1.0f / __shfl(lrunB, 4 * g + r);
    }
#pragma unroll
    for (int dt = 0; dt < 4; dt++)
#pragma unroll
        for (int r = 0; r < 4; r++) {
            ao[(size_t)(b * SEQ + qA + wid * 16 + 4 * g + r) * DIMN + h * DK + dt * 16 + c] =
                f2bf(oA[dt][r] * lrA[r]);
            ao[(size_t)(b * SEQ + qB + wid * 16 + 4 * g + r) * DIMN + h * DK + dt * 16 + c] =
                f2bf(oB[dt][r] * lrB[r]);
        }
}

// ---------------- launch ----------------
extern "C" void kernel_launch(void* const* d_in, const int* in_sizes, int n_in,
                              void* d_out, int out_size, void* d_ws, size_t ws_size,
                              hipStream_t stream) {
    const float* Q  = (const float*)d_in[0];
    const float* K  = (const float*)d_in[1];
    const float* V  = (const float*)d_in[2];
    const float* wq = (const float*)d_in[4];
    const float* wk = (const float*)d_in[5];
    const float* wv = (const float*)d_in[6];
    const float* wo = (const float*)d_in[7];
    const float* wob = (const float*)d_in[8];

    char* ws = (char*)d_ws;
    const size_t SZ_ACT = (size_t)MROWS * DIMN * 2;  // 8MB
    const size_t SZ_W   = (size_t)DIMN * DIMN * 2;   // 2MB
    unsigned short* Qb  = (unsigned short*)(ws);
    unsigned short* Kb  = (unsigned short*)(ws + SZ_ACT);
    unsigned short* Vb  = (unsigned short*)(ws + 2 * SZ_ACT);
    unsigned short* Wqb = (unsigned short*)(ws + 3 * SZ_ACT);
    unsigned short* Wkb = (unsigned short*)(ws + 3 * SZ_ACT + SZ_W);
    unsigned short* Wvb = (unsigned short*)(ws + 3 * SZ_ACT + 2 * SZ_W);
    unsigned short* Wob = (unsigned short*)(ws + 3 * SZ_ACT + 3 * SZ_W);
    unsigned short* qp  = (unsigned short*)(ws + 3 * SZ_ACT + 4 * SZ_W);
    unsigned short* kp  = (unsigned short*)(ws + 4 * SZ_ACT + 4 * SZ_W);
    unsigned short* vt  = (unsigned short*)(ws + 5 * SZ_ACT + 4 * SZ_W);  // V^T (proj3 z=2)
    unsigned short* aob = Qb;   // alias: Qb dead after Q projection

    cvt_all_kernel<<<16384, 256, 0, stream>>>(Q, K, V, wq, wk, wv, wo,
                                              Qb, Kb, Vb, Wqb, Wkb, Wvb, Wob);

    dim3 gp(MROWS / 128, DIMN / 128, 3);
    gemm_proj3_kernel<<<gp, 256, 0, stream>>>(Qb, Kb, Vb, Wqb, Wkb, Wvb, qp, kp, vt);

    attn_kernel<<<512, 256, 0, stream>>>(qp, kp, vt, aob);

    dim3 go(MROWS / 64, DIMN / 128);
    gemm_out_kernel<<<go, 256, 0, stream>>>(aob, Wob, (float*)d_out, wob);
}